// Round 19
// baseline (1016.261 us; speedup 1.0000x reference)
//
#include <hip/hip_runtime.h>
#include <hip/hip_bf16.h>

typedef __hip_bfloat16 bf16;
typedef __attribute__((ext_vector_type(8))) short short8v;
typedef __attribute__((ext_vector_type(4))) float float4v;

#define N_NODES 10000
#define E_EDGES 160000

__device__ __forceinline__ float b2f(bf16 v){ return __bfloat162float(v); }
__device__ __forceinline__ bf16 f2b(float v){ return __float2bfloat16(v); }

union U8 { int4 v; bf16 h[8]; };
union U4 { int2 v; bf16 h[4]; };

// ---- dtype-flexible external accessors (flag: 1 = bf16, 0 = f32) ----------
__device__ __forceinline__ float ldx(const void* p, size_t i, bool isb){
    return isb ? b2f(((const bf16*)p)[i]) : ((const float*)p)[i];
}
__device__ __forceinline__ void ld8(const void* p, size_t i, bool isb, float* o){
    if (isb) {
        U8 u; u.v = *reinterpret_cast<const int4*>((const bf16*)p + i);
        #pragma unroll
        for (int j = 0; j < 8; j++) o[j] = b2f(u.h[j]);
    } else {
        const float4* q = reinterpret_cast<const float4*>((const float*)p + i);
        float4 a = q[0], b = q[1];
        o[0]=a.x; o[1]=a.y; o[2]=a.z; o[3]=a.w; o[4]=b.x; o[5]=b.y; o[6]=b.z; o[7]=b.w;
    }
}
__device__ __forceinline__ void stx(void* p, size_t i, bool isb, float v){
    if (isb) ((bf16*)p)[i] = f2b(v); else ((float*)p)[i] = v;
}

// async global->LDS, 16 B/lane (HW: LDS dest = wave-uniform base + lane*16)
typedef const __attribute__((address_space(1))) void* gas_p;
typedef __attribute__((address_space(3))) void* las_p;
__device__ __forceinline__ void gl16(const bf16* g, bf16* l){
    __builtin_amdgcn_global_load_lds((gas_p)g, (las_p)l, 16, 0, 0);
}

// 4x4 in-register transpose across 4 lanes (verified r9-r18)
__device__ __forceinline__ void quadT(float* a, int t){
    float x0 = (t & 1) ? a[0] : a[1];
    float y0 = __shfl_xor(x0, 1);
    if (t & 1) a[0] = y0; else a[1] = y0;
    float x1 = (t & 1) ? a[2] : a[3];
    float y1 = __shfl_xor(x1, 1);
    if (t & 1) a[2] = y1; else a[3] = y1;
    float x2 = (t & 2) ? a[0] : a[2];
    float y2 = __shfl_xor(x2, 2);
    if (t & 2) a[0] = y2; else a[2] = y2;
    float x3 = (t & 2) ? a[1] : a[3];
    float y3 = __shfl_xor(x3, 2);
    if (t & 2) a[1] = y3; else a[3] = y3;
}

// XCD-bijective swizzle of a linear workgroup id
__device__ __forceinline__ int xcd_swz(int wg, int nwg){
    const int q = nwg >> 3, r = nwg & 7;
    const int xcd = wg & 7, ix = wg >> 3;
    return (xcd < r ? xcd * (q + 1) : r * (q + 1) + (xcd - r) * q) + ix;
}

// ---------------------------------------------------------------------------
__global__ void detect_dtype(const unsigned short* __restrict__ xw, int* __restrict__ flag){
    const int lane = threadIdx.x;  // 64 threads
    int cnt = 0;
    for (int i = lane; i < 8192; i += 64) {
        const unsigned e = (xw[i] >> 7) & 0xFF;
        if (e == 0 || (e >= 100 && e <= 140)) cnt++;
    }
    #pragma unroll
    for (int off = 32; off >= 1; off >>= 1) cnt += __shfl_xor(cnt, off);
    if (lane == 0) *flag = (cnt >= 6554) ? 1 : 0;
}

// merged convert: groups [0, 320000) -> x16; [320000, 5440000) -> lgx16
__global__ __launch_bounds__(256) void cvt_both(
    const void* __restrict__ xin, const void* __restrict__ lgin,
    bf16* __restrict__ x16, bf16* __restrict__ lgx16,
    const int* __restrict__ dflag)
{
    const bool isb = (*dflag != 0);
    const long t = (long)blockIdx.x * 256 + threadIdx.x;
    if (t >= 5440000L) return;
    float f[8];
    if (t < 320000L) {
        ld8(xin, (size_t)t * 8, isb, f);
        U8 u;
        #pragma unroll
        for (int j = 0; j < 8; j++) u.h[j] = f2b(f[j]);
        *reinterpret_cast<int4*>(&x16[t * 8]) = u.v;
    } else {
        const long s = t - 320000L;
        ld8(lgin, (size_t)s * 8, isb, f);
        U8 u;
        #pragma unroll
        for (int j = 0; j < 8; j++) u.h[j] = f2b(f[j]);
        *reinterpret_cast<int4*>(&lgx16[s * 8]) = u.v;
    }
}

// ---------------------------------------------------------------------------
// pack_all: all 12 weight matrices -> transposed bf16 [Nmat][K] in one launch.
// ---------------------------------------------------------------------------
struct PackArgs { const void* src[12]; bf16* dst[12]; };
__global__ __launch_bounds__(256) void pack_all(PackArgs pa, const int* __restrict__ dflag){
    const bool isb = (*dflag != 0);
    const long idx = (long)blockIdx.x * 256 + threadIdx.x;
    if (idx >= 1572864) return;
    int m, local, K, Nmat;
    if (idx < 524288) { m = (int)(idx >> 16); local = (int)(idx & 65535); K = 256; Nmat = 256; }
    else {
        const long j = idx - 524288;
        const int m2 = (int)(j >> 18); local = (int)(j & 262143);
        m = 8 + m2;
        if (m2 == 0 || m2 == 2) { K = 256; Nmat = 1024; } else { K = 1024; Nmat = 256; }
    }
    const int k = local / Nmat, n = local - k * Nmat;
    pa.dst[m][(size_t)n * K + k] = f2b(ldx(pa.src[m], local, isb));
}

// ---------------------------------------------------------------------------
// mgqkv: merged node-QKV + edge-QKV (verified r17/r18).
// ---------------------------------------------------------------------------
__global__ __launch_bounds__(256) void mgqkv(
    const bf16* __restrict__ An, int Mn,
    const bf16* __restrict__ Ae, int Me,
    const bf16* __restrict__ nBq, const bf16* __restrict__ nBk, const bf16* __restrict__ nBv,
    const void* __restrict__ nbias,
    const bf16* __restrict__ eBq, const bf16* __restrict__ eBk, const bf16* __restrict__ eBv,
    const void* __restrict__ ebias,
    const bf16* __restrict__ xg,
    const int* __restrict__ sidx, const int* __restrict__ didx,
    bf16* __restrict__ Cn, bf16* __restrict__ Cq, bf16* __restrict__ Ckv,
    int nby, const int* __restrict__ dflag)
{
    const bool isb = (*dflag != 0);
    __shared__ __align__(16) bf16 Al[128 * 64];
    __shared__ __align__(16) bf16 Bl[128 * 64];
    __shared__ float biasl[128];

    const int tid = threadIdx.x;
    const int lane = tid & 63, wave = tid >> 6;
    const int l15 = lane & 15, g = lane >> 4;
    const int t4 = l15 & 3, qd = l15 >> 2;
    const int wr = wave >> 1, wc = wave & 1;

    const int nwgx = gridDim.x;
    int wg = xcd_swz(blockIdx.y * nwgx + blockIdx.x, nwgx * gridDim.y);
    const int by = wg / nwgx, bx = wg % nwgx;
    const bool nodeb = (by < nby);
    const int rb = (nodeb ? by : (by - nby)) * 128;
    const int cb = bx * 128;
    const int M = nodeb ? Mn : Me;
    const bf16* A = nodeb ? An : Ae;
    const int seg = cb >> 8;
    const bf16* Bsel = nodeb ? ((seg == 0) ? nBq : ((seg == 1) ? nBk : nBv))
                             : ((seg == 0) ? eBq : ((seg == 1) ? eBk : eBv));
    const void* bias = nodeb ? nbias : ebias;
    const int cloc = cb & 255;

    if (tid < 128) {
        const int gc = cb + tid;
        biasl[tid] = (gc < 256) ? ldx(bias, gc, isb) : 0.f;
    }

    const int sp = lane & 7, sr8 = lane >> 3;
    int rls[4]; long arows[4];
    #pragma unroll
    for (int j = 0; j < 4; j++) {
        const int rl = wave * 32 + j * 8 + sr8;
        rls[j] = rl;
        const int gm = rb + rl;
        arows[j] = (gm < M) ? gm : (M - 1);
    }

    float4v acc[4][4];
    #pragma unroll
    for (int i = 0; i < 4; i++)
        #pragma unroll
        for (int j = 0; j < 4; j++)
            acc[i][j] = (float4v){0.f, 0.f, 0.f, 0.f};

    for (int k0 = 0; k0 < 256; k0 += 64) {
        #pragma unroll
        for (int j = 0; j < 4; j++) {
            const int rl = rls[j];
            const int pp = sp ^ (rl & 7);
            gl16(A + arows[j] * 256 + k0 + pp * 8,                 Al + rl * 64 + sp * 8);
            gl16(Bsel + (size_t)(cloc + rl) * 256 + k0 + pp * 8,   Bl + rl * 64 + sp * 8);
        }
        __syncthreads();
        #pragma unroll
        for (int ks = 0; ks < 2; ks++) {
            short8v av[4], bv[4];
            #pragma unroll
            for (int mi = 0; mi < 4; mi++) {
                const int row = wr * 64 + mi * 16 + l15;
                const int cp = (ks * 4 + g) ^ (row & 7);
                av[mi] = *reinterpret_cast<const short8v*>(&Al[row * 64 + cp * 8]);
            }
            #pragma unroll
            for (int ni = 0; ni < 4; ni++) {
                const int row = wc * 64 + ni * 16 + l15;
                const int cp = (ks * 4 + g) ^ (row & 7);
                bv[ni] = *reinterpret_cast<const short8v*>(&Bl[row * 64 + cp * 8]);
            }
            #pragma unroll
            for (int mi = 0; mi < 4; mi++)
                #pragma unroll
                for (int ni = 0; ni < 4; ni++)
                    acc[mi][ni] = __builtin_amdgcn_mfma_f32_16x16x32_bf16(
                        av[mi], bv[ni], acc[mi][ni], 0, 0, 0);
        }
        __syncthreads();
    }

    #pragma unroll
    for (int mi = 0; mi < 4; mi++) {
        const int grow = rb + wr * 64 + mi * 16 + g * 4 + t4;
        const bool ok = (grow < M);
        int s5 = 0, d5 = 0;
        if (!nodeb && ok) {
            if (cb < 256) s5 = sidx[grow];
            else if (cb >= 512) d5 = didx[grow];
        }
        #pragma unroll
        for (int ni = 0; ni < 4; ni++) {
            float a[4];
            #pragma unroll
            for (int r = 0; r < 4; r++) a[r] = acc[mi][ni][r];
            quadT(a, t4);
            if (!ok) continue;
            const int ct = wc * 64 + ni * 16 + qd * 4;
            const int gc = cb + ct;
            if (nodeb) {
                if (gc < 256) {
                    #pragma unroll
                    for (int u = 0; u < 4; u++) a[u] += biasl[ct + u];
                }
                U4 o;
                #pragma unroll
                for (int u = 0; u < 4; u++) o.h[u] = f2b(a[u]);
                *reinterpret_cast<int2*>(&Cn[(size_t)grow * 768 + gc]) = o.v;
            } else {
                if (gc < 256) {
                    U4 xx; xx.v = *reinterpret_cast<const int2*>(&xg[(size_t)s5 * 256 + gc]);
                    #pragma unroll
                    for (int u = 0; u < 4; u++) a[u] += biasl[ct + u] + b2f(xx.h[u]);
                    U4 o;
                    #pragma unroll
                    for (int u = 0; u < 4; u++) o.h[u] = f2b(a[u]);
                    *reinterpret_cast<int2*>(&Cq[(size_t)grow * 256 + gc]) = o.v;
                } else {
                    if (gc >= 512) {
                        U4 xx; xx.v = *reinterpret_cast<const int2*>(&xg[(size_t)d5 * 256 + (gc - 512)]);
                        #pragma unroll
                        for (int u = 0; u < 4; u++) a[u] += b2f(xx.h[u]);
                    }
                    U4 o;
                    #pragma unroll
                    for (int u = 0; u < 4; u++) o.h[u] = f2b(a[u]);
                    *reinterpret_cast<int2*>(&Ckv[(size_t)grow * 512 + (gc - 256)]) = o.v;
                }
            }
        }
    }
}

// ---------------------------------------------------------------------------
// mgattn: merged node+edge attention (verified r17/r18).
// ---------------------------------------------------------------------------
__global__ __launch_bounds__(256) void mgattn(
    const bf16* __restrict__ QKV, const int* __restrict__ lsrc,
    const bf16* __restrict__ lgx16, bf16* __restrict__ ONo,
    const bf16* __restrict__ QE, const bf16* __restrict__ KVE,
    const int* __restrict__ lgsrc, bf16* __restrict__ OEo,
    int nab)
{
    const int w = threadIdx.x >> 6, lane = threadIdx.x & 63;
    const int c4 = lane * 4;
    if (blockIdx.x < nab) {
        const int d = blockIdx.x * 4 + w;
        if (d >= N_NODES) return;
        U4 uq; uq.v = *reinterpret_cast<const int2*>(&QKV[(size_t)d * 768 + c4]);
        float q[4];
        #pragma unroll
        for (int u = 0; u < 4; u++) q[u] = b2f(uq.h[u]);
        float acc[4] = {0.f, 0.f, 0.f, 0.f};
        float z = 0.f;
        for (int j = 0; j < 16; j++) {
            const int i = d + j * N_NODES;
            const int s = lsrc[i];
            U4 ue; ue.v = *reinterpret_cast<const int2*>(&lgx16[(size_t)i * 256 + c4]);
            U4 uk; uk.v = *reinterpret_cast<const int2*>(&QKV[(size_t)s * 768 + 256 + c4]);
            U4 uv; uv.v = *reinterpret_cast<const int2*>(&QKV[(size_t)s * 768 + 512 + c4]);
            float e[4], p = 0.f;
            #pragma unroll
            for (int u = 0; u < 4; u++) {
                e[u] = b2f(ue.h[u]);
                p += (b2f(uk.h[u]) + e[u]) * q[u];
            }
            p += __shfl_xor(p, 4); p += __shfl_xor(p, 2); p += __shfl_xor(p, 1);
            const float sc = expf(fminf(fmaxf(p * 0.17677669529663687f, -10.f), 10.f));
            #pragma unroll
            for (int u = 0; u < 4; u++) acc[u] += (b2f(uv.h[u]) + e[u]) * sc;
            z += sc;
        }
        U4 o;
        const float iz = 1.f / z;
        #pragma unroll
        for (int u = 0; u < 4; u++) o.h[u] = f2b(acc[u] * iz);
        *reinterpret_cast<int2*>(&ONo[(size_t)d * 256 + c4]) = o.v;
    } else {
        const int b = (blockIdx.x - nab) * 4 + w;
        if (b >= E_EDGES) return;
        U4 uq; uq.v = *reinterpret_cast<const int2*>(&QE[(size_t)b * 256 + c4]);
        float q[4];
        #pragma unroll
        for (int u = 0; u < 4; u++) q[u] = b2f(uq.h[u]);
        float acc[4] = {0.f, 0.f, 0.f, 0.f};
        float z = 0.f;
        #pragma unroll
        for (int j = 0; j < 2; j++) {
            const int s = lgsrc[b + j * E_EDGES];
            const size_t kr = (size_t)s * 512;
            U4 uk; uk.v = *reinterpret_cast<const int2*>(&KVE[kr + c4]);
            U4 uv; uv.v = *reinterpret_cast<const int2*>(&KVE[kr + 256 + c4]);
            float p = 0.f;
            #pragma unroll
            for (int u = 0; u < 4; u++) p += b2f(uk.h[u]) * q[u];
            p += __shfl_xor(p, 4); p += __shfl_xor(p, 2); p += __shfl_xor(p, 1);
            const float sc = expf(fminf(fmaxf(p * 0.17677669529663687f, -10.f), 10.f));
            #pragma unroll
            for (int u = 0; u < 4; u++) acc[u] += b2f(uv.h[u]) * sc;
            z += sc;
        }
        U4 o;
        const float iz = 1.f / z;
        #pragma unroll
        for (int u = 0; u < 4; u++) o.h[u] = f2b(acc[u] * iz);
        *reinterpret_cast<int2*>(&OEo[(size_t)b * 256 + c4]) = o.v;
    }
}

// ---------------------------------------------------------------------------
// mgwoln: merged node+edge Wo+bias+resid -> LN -> bf16 C.
// __launch_bounds__(512,3): cap VGPR<=85 so 3 blocks/CU (24 waves) fit;
// r18 measured VGPR=100 -> only 2 blocks/CU resident (VGPR-capped).
// ---------------------------------------------------------------------------
__global__ __launch_bounds__(512, 3) void mgwoln(
    const bf16* __restrict__ An, int Mn,
    const bf16* __restrict__ Ae, int Me,
    const bf16* __restrict__ nBt, const void* __restrict__ nbias,
    const bf16* __restrict__ nresid, const void* __restrict__ nlng, const void* __restrict__ nlnb,
    bf16* __restrict__ Cn,
    const bf16* __restrict__ eBt, const void* __restrict__ ebias,
    const bf16* __restrict__ eresid, const void* __restrict__ elng, const void* __restrict__ elnb,
    bf16* __restrict__ Ce,
    int nby, const int* __restrict__ dflag)
{
    const bool isb = (*dflag != 0);
    __shared__ __align__(16) bf16 Al[128 * 64];   // 16KB (Ps overlay)
    __shared__ __align__(16) bf16 Bl[256 * 64];   // 32KB (Mr/Rsd overlay)
    __shared__ float biasl[256];
    __shared__ float lngl[256];
    __shared__ float lnbl[256];

    const int tid = threadIdx.x;
    const int lane = tid & 63, wave = tid >> 6;
    const int l15 = lane & 15, g = lane >> 4;
    const int t4 = l15 & 3, qd = l15 >> 2;
    const int wr = wave >> 2, wc = wave & 3;   // 2 x 4 wave grid

    const int wg = xcd_swz(blockIdx.y, gridDim.y);
    const bool nodeb = (wg < nby);
    const int rb = (nodeb ? wg : (wg - nby)) * 128;
    const int M = nodeb ? Mn : Me;
    const bf16* A = nodeb ? An : Ae;
    const bf16* Bt = nodeb ? nBt : eBt;
    const void* bias = nodeb ? nbias : ebias;
    const bf16* resid = nodeb ? nresid : eresid;
    const void* lng = nodeb ? nlng : elng;
    const void* lnb = nodeb ? nlnb : elnb;
    bf16* C = nodeb ? Cn : Ce;

    if (tid < 256) {
        biasl[tid] = ldx(bias, tid, isb);
        lngl[tid]  = ldx(lng,  tid, isb);
        lnbl[tid]  = ldx(lnb,  tid, isb);
    }

    const int sp = lane & 7, sr8 = lane >> 3;
    int rlA[2]; long arA[2];
    #pragma unroll
    for (int j = 0; j < 2; j++) {
        const int rl = wave * 16 + j * 8 + sr8;
        rlA[j] = rl;
        const int gm = rb + rl;
        arA[j] = (gm < M) ? gm : (M - 1);
    }
    int rlB[4];
    #pragma unroll
    for (int j = 0; j < 4; j++) rlB[j] = wave * 32 + j * 8 + sr8;

    float4v acc[4][4];
    #pragma unroll
    for (int i = 0; i < 4; i++)
        #pragma unroll
        for (int j = 0; j < 4; j++)
            acc[i][j] = (float4v){0.f, 0.f, 0.f, 0.f};

    for (int k0 = 0; k0 < 256; k0 += 64) {
        #pragma unroll
        for (int j = 0; j < 2; j++) {
            const int pp = sp ^ (rlA[j] & 7);
            gl16(A + arA[j] * 256 + k0 + pp * 8, Al + rlA[j] * 64 + sp * 8);
        }
        #pragma unroll
        for (int j = 0; j < 4; j++) {
            const int pp = sp ^ (rlB[j] & 7);
            gl16(Bt + (size_t)rlB[j] * 256 + k0 + pp * 8, Bl + rlB[j] * 64 + sp * 8);
        }
        __syncthreads();
        #pragma unroll
        for (int ks = 0; ks < 2; ks++) {
            short8v av[4], bv[4];
            #pragma unroll
            for (int mi = 0; mi < 4; mi++) {
                const int row = wr * 64 + mi * 16 + l15;
                const int cp = (ks * 4 + g) ^ (row & 7);
                av[mi] = *reinterpret_cast<const short8v*>(&Al[row * 64 + cp * 8]);
            }
            #pragma unroll
            for (int ni = 0; ni < 4; ni++) {
                const int row = wc * 64 + ni * 16 + l15;
                const int cp = (ks * 4 + g) ^ (row & 7);
                bv[ni] = *reinterpret_cast<const short8v*>(&Bl[row * 64 + cp * 8]);
            }
            #pragma unroll
            for (int mi = 0; mi < 4; mi++)
                #pragma unroll
                for (int ni = 0; ni < 4; ni++)
                    acc[mi][ni] = __builtin_amdgcn_mfma_f32_16x16x32_bf16(
                        av[mi], bv[ni], acc[mi][ni], 0, 0, 0);
        }
        __syncthreads();
    }

    float s1[4] = {0.f,0.f,0.f,0.f}, s2[4] = {0.f,0.f,0.f,0.f};
    #pragma unroll
    for (int mi = 0; mi < 4; mi++) {
        const int grow = rb + wr * 64 + mi * 16 + g * 4 + t4;
        const bool ok = (grow < M);
        #pragma unroll
        for (int ni = 0; ni < 4; ni++) {
            float a[4];
            #pragma unroll
            for (int r = 0; r < 4; r++) a[r] = acc[mi][ni][r];
            quadT(a, t4);
            const int ct = wc * 64 + ni * 16 + qd * 4;
            U4 rr; rr.v = make_int2(0, 0);
            if (ok) rr.v = *reinterpret_cast<const int2*>(&resid[(size_t)grow * 256 + ct]);
            #pragma unroll
            for (int u = 0; u < 4; u++) {
                a[u] += biasl[ct + u] + b2f(rr.h[u]);
                s1[mi] += a[u];
                s2[mi] += a[u] * a[u];
                acc[mi][ni][u] = a[u];
            }
        }
    }
    float* Ps1 = (float*)Al;          // [16][128]
    float* Ps2 = Ps1 + 2048;
    #pragma unroll
    for (int mi = 0; mi < 4; mi++) {
        const int rowl = wr * 64 + mi * 16 + g * 4 + t4;
        Ps1[(wc * 4 + qd) * 128 + rowl] = s1[mi];
        Ps2[(wc * 4 + qd) * 128 + rowl] = s2[mi];
    }
    __syncthreads();
    float* Mr  = (float*)Bl;
    float* Rsd = Mr + 128;
    if (tid < 128) {
        float a1 = 0.f, a2 = 0.f;
        #pragma unroll
        for (int k = 0; k < 16; k++) { a1 += Ps1[k * 128 + tid]; a2 += Ps2[k * 128 + tid]; }
        const float mn = a1 * (1.f / 256.f);
        const float var = a2 * (1.f / 256.f) - mn * mn;
        Mr[tid] = mn;
        Rsd[tid] = rsqrtf(fmaxf(var, 0.f) + 1e-5f);
    }
    __syncthreads();
    #pragma unroll
    for (int mi = 0; mi < 4; mi++) {
        const int rowl = wr * 64 + mi * 16 + g * 4 + t4;
        const int grow = rb + rowl;
        if (grow >= M) continue;
        const float mn = Mr[rowl], rd = Rsd[rowl];
        #pragma unroll
        for (int ni = 0; ni < 4; ni++) {
            const int ct = wc * 64 + ni * 16 + qd * 4;
            U4 ob;
            #pragma unroll
            for (int u = 0; u < 4; u++)
                ob.h[u] = f2b((acc[mi][ni][u] - mn) * rd * lngl[ct + u] + lnbl[ct + u]);
            *reinterpret_cast<int2*>(&C[(size_t)grow * 256 + ct]) = ob.v;
        }
    }
}

// ---------------------------------------------------------------------------
// mgffn1: merged node+edge FFN1 relu(+bias), K=256, NC=1024 (verified r17/r18).
// ---------------------------------------------------------------------------
__global__ __launch_bounds__(256) void mgffn1(
    const bf16* __restrict__ An, int Mn,
    const bf16* __restrict__ Ae, int Me,
    const bf16* __restrict__ nBt, const void* __restrict__ nbias, bf16* __restrict__ Cn,
    const bf16* __restrict__ eBt, const void* __restrict__ ebias, bf16* __restrict__ Ce,
    int nby, const int* __restrict__ dflag)
{
    const bool isb = (*dflag != 0);
    __shared__ __align__(16) bf16 Al[128 * 64];
    __shared__ __align__(16) bf16 Bl[128 * 64];
    __shared__ float biasl[128];

    const int tid = threadIdx.x;
    const int lane = tid & 63, wave = tid >> 6;
    const int l15 = lane & 15, g = lane >> 4;
    const int t4 = l15 & 3, qd = l15 >> 2;
    const int wr = wave >> 1, wc = wave & 1;

    const int nwgx = gridDim.x;   // 8
    int wg = xcd_swz(blockIdx.y * nwgx + blockIdx.x, nwgx * gridDim.y);
    const int by = wg / nwgx, bx = wg % nwgx;
    const bool nodeb = (by < nby);
    const int rb = (nodeb ? by : (by - nby)) * 128;
    const int cb = bx * 128;
    const int M = nodeb ? Mn : Me;
    const bf16* A = nodeb ? An : Ae;
    const bf16* Bt = nodeb ? nBt : eBt;
    const void* bias = nodeb ? nbias : ebias;
    bf16* C = nodeb ? Cn : Ce;

    if (tid < 128) biasl[tid] = ldx(bias, cb + tid, isb);

    const int sp = lane & 7, sr8 = lane >> 3;
    int rls[4]; long arows[4];
    #pragma unroll
    for (int j = 0; j < 4; j++) {
        const int rl = wave * 32 + j * 8 + sr8;
        rls[j] = rl;
        const int gm = rb + rl;
        arows[j] = (gm < M) ? gm : (M - 1);
    }

    float4v acc[4][4];
    #pragma unroll
    for (int i = 0; i < 4; i++)
        #pragma unroll
        for (int j = 0; j < 4; j++)
            acc[i][j] = (float4v){0.f, 0.f, 0.f, 0.f};

    for (int k0 = 0; k0 < 256; k0 += 64) {
        #pragma unroll
        for (int j = 0; j < 4; j++) {
            const int rl = rls[j];
            const int pp = sp ^ (rl & 7);
            gl16(A + arows[j] * 256 + k0 + pp * 8,              Al + rl * 64 + sp * 8);
            gl16(Bt + (size_t)(cb + rl) * 256 + k0 + pp * 8,    Bl + rl * 64 + sp * 8);
        }
        __syncthreads();
        #pragma unroll
        for (int ks = 0; ks < 2; ks++) {
            short8v av[4], bv[4];
            #pragma unroll
            for (int mi = 0; mi < 4; mi++) {
                const int row = wr * 64 + mi * 16 + l15;
                const int cp = (ks * 4 + g) ^ (row & 7);
                av[mi] = *reinterpret_cast<const short8v*>(&Al[row * 64 + cp * 8]);
            }
            #pragma unroll
            for (int ni = 0; ni < 4; ni++) {
                const int row = wc * 64 + ni * 16 + l15;
                const int cp = (ks * 4 + g) ^ (row & 7);
                bv[ni] = *reinterpret_cast<const short8v*>(&Bl[row * 64 + cp * 8]);
            }
            #pragma unroll
            for (int mi = 0; mi < 4; mi++)
                #pragma unroll
                for (int ni = 0; ni < 4; ni++)
                    acc[mi][ni] = __builtin_amdgcn_mfma_f32_16x16x32_bf16(
                        av[mi], bv[ni], acc[mi][ni], 0, 0, 0);
        }
        __syncthreads();
    }

    #pragma unroll
    for (int mi = 0; mi < 4; mi++) {
        const int grow = rb + wr * 64 + mi * 16 + g * 4 + t4;
        const bool ok = (grow < M);
        #pragma unroll
        for (int ni = 0; ni < 4; ni++) {
            float a[4];
            #pragma unroll
            for (int r = 0; r < 4; r++) a[r] = acc[mi][ni][r];
            quadT(a, t4);
            if (!ok) continue;
            const int ct = wc * 64 + ni * 16 + qd * 4;
            U4 o;
            #pragma unroll
            for (int u = 0; u < 4; u++) o.h[u] = f2b(fmaxf(a[u] + biasl[ct + u], 0.f));
            *reinterpret_cast<int2*>(&C[(size_t)grow * 1024 + cb + ct]) = o.v;
        }
    }
}

// ---------------------------------------------------------------------------
// mgffn2: merged node+edge FFN2(+bias+resid) -> LN -> dtype-flex out.
// __launch_bounds__(512,3): cap VGPR<=85 for 3 blocks/CU (see mgwoln note).
// ---------------------------------------------------------------------------
__global__ __launch_bounds__(512, 3) void mgffn2(
    const bf16* __restrict__ An, int Mn,
    const bf16* __restrict__ Ae, int Me,
    const bf16* __restrict__ nBt, const void* __restrict__ nbias,
    const bf16* __restrict__ nresid, const void* __restrict__ nlng, const void* __restrict__ nlnb,
    long nobase,
    const bf16* __restrict__ eBt, const void* __restrict__ ebias,
    const bf16* __restrict__ eresid, const void* __restrict__ elng, const void* __restrict__ elnb,
    long eobase,
    void* __restrict__ outv,
    int nby, const int* __restrict__ dflag)
{
    const bool isb = (*dflag != 0);
    __shared__ __align__(16) bf16 Al[128 * 64];   // 16KB (Ps overlay)
    __shared__ __align__(16) bf16 Bl[256 * 64];   // 32KB (Mr/Rsd overlay)
    __shared__ float biasl[256];
    __shared__ float lngl[256];
    __shared__ float lnbl[256];

    const int tid = threadIdx.x;
    const int lane = tid & 63, wave = tid >> 6;
    const int l15 = lane & 15, g = lane >> 4;
    const int t4 = l15 & 3, qd = l15 >> 2;
    const int wr = wave >> 2, wc = wave & 3;   // 2 x 4 wave grid

    const int wg = xcd_swz(blockIdx.y, gridDim.y);
    const bool nodeb = (wg < nby);
    const int rb = (nodeb ? wg : (wg - nby)) * 128;
    const int M = nodeb ? Mn : Me;
    const bf16* A = nodeb ? An : Ae;
    const bf16* Bt = nodeb ? nBt : eBt;
    const void* bias = nodeb ? nbias : ebias;
    const bf16* resid = nodeb ? nresid : eresid;
    const void* lng = nodeb ? nlng : elng;
    const void* lnb = nodeb ? nlnb : elnb;
    const long obase = nodeb ? nobase : eobase;

    if (tid < 256) {
        biasl[tid] = ldx(bias, tid, isb);
        lngl[tid]  = ldx(lng,  tid, isb);
        lnbl[tid]  = ldx(lnb,  tid, isb);
    }

    const int sp = lane & 7, sr8 = lane >> 3;
    int rlA[2]; long arA[2];
    #pragma unroll
    for (int j = 0; j < 2; j++) {
        const int rl = wave * 16 + j * 8 + sr8;
        rlA[j] = rl;
        const int gm = rb + rl;
        arA[j] = (gm < M) ? gm : (M - 1);
    }
    int rlB[4];
    #pragma unroll
    for (int j = 0; j < 4; j++) rlB[j] = wave * 32 + j * 8 + sr8;

    float4v acc[4][4];
    #pragma unroll
    for (int i = 0; i < 4; i++)
        #pragma unroll
        for (int j = 0; j < 4; j++)
            acc[i][j] = (float4v){0.f, 0.f, 0.f, 0.f};

    for (int k0 = 0; k0 < 1024; k0 += 64) {
        #pragma unroll
        for (int j = 0; j < 2; j++) {
            const int pp = sp ^ (rlA[j] & 7);
            gl16(A + arA[j] * 1024 + k0 + pp * 8, Al + rlA[j] * 64 + sp * 8);
        }
        #pragma unroll
        for (int j = 0; j < 4; j++) {
            const int pp = sp ^ (rlB[j] & 7);
            gl16(Bt + (size_t)rlB[j] * 1024 + k0 + pp * 8, Bl + rlB[j] * 64 + sp * 8);
        }
        __syncthreads();
        #pragma unroll
        for (int ks = 0; ks < 2; ks++) {
            short8v av[4], bv[4];
            #pragma unroll
            for (int mi = 0; mi < 4; mi++) {
                const int row = wr * 64 + mi * 16 + l15;
                const int cp = (ks * 4 + g) ^ (row & 7);
                av[mi] = *reinterpret_cast<const short8v*>(&Al[row * 64 + cp * 8]);
            }
            #pragma unroll
            for (int ni = 0; ni < 4; ni++) {
                const int row = wc * 64 + ni * 16 + l15;
                const int cp = (ks * 4 + g) ^ (row & 7);
                bv[ni] = *reinterpret_cast<const short8v*>(&Bl[row * 64 + cp * 8]);
            }
            #pragma unroll
            for (int mi = 0; mi < 4; mi++)
                #pragma unroll
                for (int ni = 0; ni < 4; ni++)
                    acc[mi][ni] = __builtin_amdgcn_mfma_f32_16x16x32_bf16(
                        av[mi], bv[ni], acc[mi][ni], 0, 0, 0);
        }
        __syncthreads();
    }

    float s1[4] = {0.f,0.f,0.f,0.f}, s2[4] = {0.f,0.f,0.f,0.f};
    #pragma unroll
    for (int mi = 0; mi < 4; mi++) {
        const int grow = rb + wr * 64 + mi * 16 + g * 4 + t4;
        const bool ok = (grow < M);
        #pragma unroll
        for (int ni = 0; ni < 4; ni++) {
            float a[4];
            #pragma unroll
            for (int r = 0; r < 4; r++) a[r] = acc[mi][ni][r];
            quadT(a, t4);
            const int ct = wc * 64 + ni * 16 + qd * 4;
            U4 rr; rr.v = make_int2(0, 0);
            if (ok) rr.v = *reinterpret_cast<const int2*>(&resid[(size_t)grow * 256 + ct]);
            #pragma unroll
            for (int u = 0; u < 4; u++) {
                a[u] += biasl[ct + u] + b2f(rr.h[u]);
                s1[mi] += a[u];
                s2[mi] += a[u] * a[u];
                acc[mi][ni][u] = a[u];
            }
        }
    }
    float* Ps1 = (float*)Al;          // [16][128]
    float* Ps2 = Ps1 + 2048;
    #pragma unroll
    for (int mi = 0; mi < 4; mi++) {
        const int rowl = wr * 64 + mi * 16 + g * 4 + t4;
        Ps1[(wc * 4 + qd) * 128 + rowl] = s1[mi];
        Ps2[(wc * 4 + qd) * 128 + rowl] = s2[mi];
    }
    __syncthreads();
    float* Mr  = (float*)Bl;
    float* Rsd = Mr + 128;
    if (tid < 128) {
        float a1 = 0.f, a2 = 0.f;
        #pragma unroll
        for (int k = 0; k < 16; k++) { a1 += Ps1[k * 128 + tid]; a2 += Ps2[k * 128 + tid]; }
        const float mn = a1 * (1.f / 256.f);
        const float var = a2 * (1.f / 256.f) - mn * mn;
        Mr[tid] = mn;
        Rsd[tid] = rsqrtf(fmaxf(var, 0.f) + 1e-5f);
    }
    __syncthreads();
    #pragma unroll
    for (int mi = 0; mi < 4; mi++) {
        const int rowl = wr * 64 + mi * 16 + g * 4 + t4;
        const int grow = rb + rowl;
        if (grow >= M) continue;
        const float mn = Mr[rowl], rd = Rsd[rowl];
        #pragma unroll
        for (int ni = 0; ni < 4; ni++) {
            const int ct = wc * 64 + ni * 16 + qd * 4;
            float o[4];
            #pragma unroll
            for (int u = 0; u < 4; u++)
                o[u] = (acc[mi][ni][u] - mn) * rd * lngl[ct + u] + lnbl[ct + u];
            if (isb) {
                U4 ob;
                #pragma unroll
                for (int u = 0; u < 4; u++) ob.h[u] = f2b(o[u]);
                *reinterpret_cast<int2*>((bf16*)outv + obase + (size_t)grow * 256 + ct) = ob.v;
            } else {
                float4 f4 = make_float4(o[0], o[1], o[2], o[3]);
                *reinterpret_cast<float4*>((float*)outv + obase + (size_t)grow * 256 + ct) = f4;
            }
        }
    }
}

// ---------------------------------------------------------------------------
extern "C" void kernel_launch(void* const* d_in, const int* in_sizes, int n_in,
                              void* d_out, int out_size, void* d_ws, size_t ws_size,
                              hipStream_t stream)
{
    const void* x   = d_in[0];
    const void* lgx = d_in[1];
    const int* local_src = (const int*)d_in[3];
    const int* lg_src    = (const int*)d_in[5];
    const int* src_ids   = (const int*)d_in[7];
    const int* dst_ids   = (const int*)d_in[8];

    const void *nWq = d_in[9],  *nbq = d_in[10], *nWk = d_in[11], *nWv = d_in[12],
               *nWo = d_in[13], *nbo = d_in[14], *nln1g = d_in[15], *nln1b = d_in[16],
               *nW1 = d_in[17], *nb1 = d_in[18], *nW2 = d_in[19], *nb2 = d_in[20],
               *nln2g = d_in[21], *nln2b = d_in[22];
    const void *eWq = d_in[23], *ebq = d_in[24], *eWk = d_in[25], *eWv = d_in[26],
               *eWo = d_in[27], *ebo = d_in[28], *eln1g = d_in[29], *eln1b = d_in[30],
               *eW1 = d_in[31], *eb1 = d_in[32], *eW2 = d_in[33], *eb2 = d_in[34],
               *eln2g = d_in[35], *eln2b = d_in[36];

    const dim3 blk(256);
    const dim3 blk2(512);

    // ===== ws layout (elements, bf16).  FE overlays [KVE..OE) which is dead
    // by the time mgffn1 runs.  fixed total = 545.9 MB < ~696 MB measured.
    int* dflag = (int*)d_ws;
    detect_dtype<<<1, 64, 0, stream>>>((const unsigned short*)x, dflag);

    bf16* pk = (bf16*)((char*)d_ws + 256);
    bf16 *pnWq = pk,            *pnWk = pk + 65536,   *pnWv = pk + 131072,
         *pnWo = pk + 196608,   *peWq = pk + 262144,  *peWk = pk + 327680,
         *peWv = pk + 393216,   *peWo = pk + 458752,
         *pnW1 = pk + 524288,   *pnW2 = pk + 786432,
         *peW1 = pk + 1048576,  *peW2 = pk + 1310720;
    bf16* x16   = pk + 1572864;                        //  2,560,000 elems
    bf16* lgx16 = x16 + 2560000;                       // 40,960,000
    bf16* KVE   = lgx16 + 40960000;                    // 81,920,000  (overlay start)
    bf16* QE    = KVE + 81920000;                      // 40,960,000
    bf16* QKVN  = QE + 40960000;                       //  7,680,000
    bf16* OE    = QKVN + 7680000;                      // 40,960,000  (overlay end: 171.52M elems)
    bf16* ON    = OE + 40960000;                       //  2,560,000
    bf16* HN    = ON + 2560000;                        //  2,560,000
    bf16* FN    = HN + 2560000;                        // 10,240,000
    bf16* HE    = FN + 10240000;                       // 40,960,000
    bf16* FE    = KVE;                                 // overlay: 163,840,000 <= 171,520,000

    cvt_both<<<21250, blk, 0, stream>>>(x, lgx, x16, lgx16, dflag);

    PackArgs pa;
    pa.src[0] = nWq; pa.src[1] = nWk; pa.src[2] = nWv; pa.src[3] = nWo;
    pa.src[4] = eWq; pa.src[5] = eWk; pa.src[6] = eWv; pa.src[7] = eWo;
    pa.src[8] = nW1; pa.src[9] = nW2; pa.src[10] = eW1; pa.src[11] = eW2;
    pa.dst[0] = pnWq; pa.dst[1] = pnWk; pa.dst[2] = pnWv; pa.dst[3] = pnWo;
    pa.dst[4] = peWq; pa.dst[5] = peWk; pa.dst[6] = peWv; pa.dst[7] = peWo;
    pa.dst[8] = pnW1; pa.dst[9] = pnW2; pa.dst[10] = peW1; pa.dst[11] = peW2;
    pack_all<<<6144, blk, 0, stream>>>(pa, dflag);

    const int nby = (N_NODES + 127) / 128;   // 79
    const int eby = (E_EDGES + 127) / 128;   // 1250

    // stage 1: merged QKV (node + edge)
    mgqkv<<<dim3(6, nby + eby), blk, 0, stream>>>(
        x16, N_NODES, lgx16, E_EDGES,
        pnWq, pnWk, pnWv, nbq,
        peWq, peWk, peWv, ebq,
        x16, src_ids, dst_ids,
        QKVN, QE, KVE, nby, dflag);

    // stage 2: merged attention
    const int nab = (N_NODES + 3) / 4;        // 2500
    const int eab = (E_EDGES + 3) / 4;        // 40000
    mgattn<<<nab + eab, blk, 0, stream>>>(
        QKVN, local_src, lgx16, ON, QE, KVE, lg_src, OE, nab);

    // stage 3: merged Wo + LN1
    mgwoln<<<dim3(1, nby + eby), blk2, 0, stream>>>(
        ON, N_NODES, OE, E_EDGES,
        pnWo, nbo, x16, nln1g, nln1b, HN,
        peWo, ebo, lgx16, eln1g, eln1b, HE,
        nby, dflag);

    // stage 4: merged FFN1 (full E, FE overlays dead buffers)
    mgffn1<<<dim3(8, nby + eby), blk, 0, stream>>>(
        HN, N_NODES, HE, E_EDGES,
        pnW1, nb1, FN,
        peW1, eb1, FE,
        nby, dflag);

    // stage 5: merged FFN2 + LN2 -> out
    mgffn2<<<dim3(1, nby + eby), blk2, 0, stream>>>(
        FN, N_NODES, FE, E_EDGES,
        pnW2, nb2, HN, nln2g, nln2b, 0L,
        peW2, eb2, HE, eln2g, eln2b, (long)N_NODES * 256,
        d_out, nby, dflag);
}

// Round 20
// 955.909 us; speedup vs baseline: 1.0631x; 1.0631x over previous
//
#include <hip/hip_runtime.h>
#include <hip/hip_bf16.h>

typedef __hip_bfloat16 bf16;
typedef __attribute__((ext_vector_type(8))) short short8v;
typedef __attribute__((ext_vector_type(4))) float float4v;

#define N_NODES 10000
#define E_EDGES 160000

__device__ __forceinline__ float b2f(bf16 v){ return __bfloat162float(v); }
__device__ __forceinline__ bf16 f2b(float v){ return __float2bfloat16(v); }

union U8 { int4 v; bf16 h[8]; };
union U4 { int2 v; bf16 h[4]; };

// ---- dtype-flexible external accessors (flag: 1 = bf16, 0 = f32) ----------
__device__ __forceinline__ float ldx(const void* p, size_t i, bool isb){
    return isb ? b2f(((const bf16*)p)[i]) : ((const float*)p)[i];
}
__device__ __forceinline__ void ld8(const void* p, size_t i, bool isb, float* o){
    if (isb) {
        U8 u; u.v = *reinterpret_cast<const int4*>((const bf16*)p + i);
        #pragma unroll
        for (int j = 0; j < 8; j++) o[j] = b2f(u.h[j]);
    } else {
        const float4* q = reinterpret_cast<const float4*>((const float*)p + i);
        float4 a = q[0], b = q[1];
        o[0]=a.x; o[1]=a.y; o[2]=a.z; o[3]=a.w; o[4]=b.x; o[5]=b.y; o[6]=b.z; o[7]=b.w;
    }
}
__device__ __forceinline__ void stx(void* p, size_t i, bool isb, float v){
    if (isb) ((bf16*)p)[i] = f2b(v); else ((float*)p)[i] = v;
}

// async global->LDS, 16 B/lane (HW: LDS dest = wave-uniform base + lane*16)
typedef const __attribute__((address_space(1))) void* gas_p;
typedef __attribute__((address_space(3))) void* las_p;
__device__ __forceinline__ void gl16(const bf16* g, bf16* l){
    __builtin_amdgcn_global_load_lds((gas_p)g, (las_p)l, 16, 0, 0);
}

// 4x4 in-register transpose across 4 lanes (verified r9-r18)
__device__ __forceinline__ void quadT(float* a, int t){
    float x0 = (t & 1) ? a[0] : a[1];
    float y0 = __shfl_xor(x0, 1);
    if (t & 1) a[0] = y0; else a[1] = y0;
    float x1 = (t & 1) ? a[2] : a[3];
    float y1 = __shfl_xor(x1, 1);
    if (t & 1) a[2] = y1; else a[3] = y1;
    float x2 = (t & 2) ? a[0] : a[2];
    float y2 = __shfl_xor(x2, 2);
    if (t & 2) a[0] = y2; else a[2] = y2;
    float x3 = (t & 2) ? a[1] : a[3];
    float y3 = __shfl_xor(x3, 2);
    if (t & 2) a[1] = y3; else a[3] = y3;
}

// XCD-bijective swizzle of a linear workgroup id
__device__ __forceinline__ int xcd_swz(int wg, int nwg){
    const int q = nwg >> 3, r = nwg & 7;
    const int xcd = wg & 7, ix = wg >> 3;
    return (xcd < r ? xcd * (q + 1) : r * (q + 1) + (xcd - r) * q) + ix;
}

// ---------------------------------------------------------------------------
__global__ void detect_dtype(const unsigned short* __restrict__ xw, int* __restrict__ flag){
    const int lane = threadIdx.x;  // 64 threads
    int cnt = 0;
    for (int i = lane; i < 8192; i += 64) {
        const unsigned e = (xw[i] >> 7) & 0xFF;
        if (e == 0 || (e >= 100 && e <= 140)) cnt++;
    }
    #pragma unroll
    for (int off = 32; off >= 1; off >>= 1) cnt += __shfl_xor(cnt, off);
    if (lane == 0) *flag = (cnt >= 6554) ? 1 : 0;
}

// merged convert: groups [0, 320000) -> x16; [320000, 5440000) -> lgx16
__global__ __launch_bounds__(256) void cvt_both(
    const void* __restrict__ xin, const void* __restrict__ lgin,
    bf16* __restrict__ x16, bf16* __restrict__ lgx16,
    const int* __restrict__ dflag)
{
    const bool isb = (*dflag != 0);
    const long t = (long)blockIdx.x * 256 + threadIdx.x;
    if (t >= 5440000L) return;
    float f[8];
    if (t < 320000L) {
        ld8(xin, (size_t)t * 8, isb, f);
        U8 u;
        #pragma unroll
        for (int j = 0; j < 8; j++) u.h[j] = f2b(f[j]);
        *reinterpret_cast<int4*>(&x16[t * 8]) = u.v;
    } else {
        const long s = t - 320000L;
        ld8(lgin, (size_t)s * 8, isb, f);
        U8 u;
        #pragma unroll
        for (int j = 0; j < 8; j++) u.h[j] = f2b(f[j]);
        *reinterpret_cast<int4*>(&lgx16[s * 8]) = u.v;
    }
}

// ---------------------------------------------------------------------------
// pack_all: all 12 weight matrices -> transposed bf16 [Nmat][K] in one launch.
// ---------------------------------------------------------------------------
struct PackArgs { const void* src[12]; bf16* dst[12]; };
__global__ __launch_bounds__(256) void pack_all(PackArgs pa, const int* __restrict__ dflag){
    const bool isb = (*dflag != 0);
    const long idx = (long)blockIdx.x * 256 + threadIdx.x;
    if (idx >= 1572864) return;
    int m, local, K, Nmat;
    if (idx < 524288) { m = (int)(idx >> 16); local = (int)(idx & 65535); K = 256; Nmat = 256; }
    else {
        const long j = idx - 524288;
        const int m2 = (int)(j >> 18); local = (int)(j & 262143);
        m = 8 + m2;
        if (m2 == 0 || m2 == 2) { K = 256; Nmat = 1024; } else { K = 1024; Nmat = 256; }
    }
    const int k = local / Nmat, n = local - k * Nmat;
    pa.dst[m][(size_t)n * K + k] = f2b(ldx(pa.src[m], local, isb));
}

// ---------------------------------------------------------------------------
// mgqkv: merged node-QKV + edge-QKV (verified r17/r18).
// ---------------------------------------------------------------------------
__global__ __launch_bounds__(256) void mgqkv(
    const bf16* __restrict__ An, int Mn,
    const bf16* __restrict__ Ae, int Me,
    const bf16* __restrict__ nBq, const bf16* __restrict__ nBk, const bf16* __restrict__ nBv,
    const void* __restrict__ nbias,
    const bf16* __restrict__ eBq, const bf16* __restrict__ eBk, const bf16* __restrict__ eBv,
    const void* __restrict__ ebias,
    const bf16* __restrict__ xg,
    const int* __restrict__ sidx, const int* __restrict__ didx,
    bf16* __restrict__ Cn, bf16* __restrict__ Cq, bf16* __restrict__ Ckv,
    int nby, const int* __restrict__ dflag)
{
    const bool isb = (*dflag != 0);
    __shared__ __align__(16) bf16 Al[128 * 64];
    __shared__ __align__(16) bf16 Bl[128 * 64];
    __shared__ float biasl[128];

    const int tid = threadIdx.x;
    const int lane = tid & 63, wave = tid >> 6;
    const int l15 = lane & 15, g = lane >> 4;
    const int t4 = l15 & 3, qd = l15 >> 2;
    const int wr = wave >> 1, wc = wave & 1;

    const int nwgx = gridDim.x;
    int wg = xcd_swz(blockIdx.y * nwgx + blockIdx.x, nwgx * gridDim.y);
    const int by = wg / nwgx, bx = wg % nwgx;
    const bool nodeb = (by < nby);
    const int rb = (nodeb ? by : (by - nby)) * 128;
    const int cb = bx * 128;
    const int M = nodeb ? Mn : Me;
    const bf16* A = nodeb ? An : Ae;
    const int seg = cb >> 8;
    const bf16* Bsel = nodeb ? ((seg == 0) ? nBq : ((seg == 1) ? nBk : nBv))
                             : ((seg == 0) ? eBq : ((seg == 1) ? eBk : eBv));
    const void* bias = nodeb ? nbias : ebias;
    const int cloc = cb & 255;

    if (tid < 128) {
        const int gc = cb + tid;
        biasl[tid] = (gc < 256) ? ldx(bias, gc, isb) : 0.f;
    }

    const int sp = lane & 7, sr8 = lane >> 3;
    int rls[4]; long arows[4];
    #pragma unroll
    for (int j = 0; j < 4; j++) {
        const int rl = wave * 32 + j * 8 + sr8;
        rls[j] = rl;
        const int gm = rb + rl;
        arows[j] = (gm < M) ? gm : (M - 1);
    }

    float4v acc[4][4];
    #pragma unroll
    for (int i = 0; i < 4; i++)
        #pragma unroll
        for (int j = 0; j < 4; j++)
            acc[i][j] = (float4v){0.f, 0.f, 0.f, 0.f};

    for (int k0 = 0; k0 < 256; k0 += 64) {
        #pragma unroll
        for (int j = 0; j < 4; j++) {
            const int rl = rls[j];
            const int pp = sp ^ (rl & 7);
            gl16(A + arows[j] * 256 + k0 + pp * 8,                 Al + rl * 64 + sp * 8);
            gl16(Bsel + (size_t)(cloc + rl) * 256 + k0 + pp * 8,   Bl + rl * 64 + sp * 8);
        }
        __syncthreads();
        #pragma unroll
        for (int ks = 0; ks < 2; ks++) {
            short8v av[4], bv[4];
            #pragma unroll
            for (int mi = 0; mi < 4; mi++) {
                const int row = wr * 64 + mi * 16 + l15;
                const int cp = (ks * 4 + g) ^ (row & 7);
                av[mi] = *reinterpret_cast<const short8v*>(&Al[row * 64 + cp * 8]);
            }
            #pragma unroll
            for (int ni = 0; ni < 4; ni++) {
                const int row = wc * 64 + ni * 16 + l15;
                const int cp = (ks * 4 + g) ^ (row & 7);
                bv[ni] = *reinterpret_cast<const short8v*>(&Bl[row * 64 + cp * 8]);
            }
            #pragma unroll
            for (int mi = 0; mi < 4; mi++)
                #pragma unroll
                for (int ni = 0; ni < 4; ni++)
                    acc[mi][ni] = __builtin_amdgcn_mfma_f32_16x16x32_bf16(
                        av[mi], bv[ni], acc[mi][ni], 0, 0, 0);
        }
        __syncthreads();
    }

    #pragma unroll
    for (int mi = 0; mi < 4; mi++) {
        const int grow = rb + wr * 64 + mi * 16 + g * 4 + t4;
        const bool ok = (grow < M);
        int s5 = 0, d5 = 0;
        if (!nodeb && ok) {
            if (cb < 256) s5 = sidx[grow];
            else if (cb >= 512) d5 = didx[grow];
        }
        #pragma unroll
        for (int ni = 0; ni < 4; ni++) {
            float a[4];
            #pragma unroll
            for (int r = 0; r < 4; r++) a[r] = acc[mi][ni][r];
            quadT(a, t4);
            if (!ok) continue;
            const int ct = wc * 64 + ni * 16 + qd * 4;
            const int gc = cb + ct;
            if (nodeb) {
                if (gc < 256) {
                    #pragma unroll
                    for (int u = 0; u < 4; u++) a[u] += biasl[ct + u];
                }
                U4 o;
                #pragma unroll
                for (int u = 0; u < 4; u++) o.h[u] = f2b(a[u]);
                *reinterpret_cast<int2*>(&Cn[(size_t)grow * 768 + gc]) = o.v;
            } else {
                if (gc < 256) {
                    U4 xx; xx.v = *reinterpret_cast<const int2*>(&xg[(size_t)s5 * 256 + gc]);
                    #pragma unroll
                    for (int u = 0; u < 4; u++) a[u] += biasl[ct + u] + b2f(xx.h[u]);
                    U4 o;
                    #pragma unroll
                    for (int u = 0; u < 4; u++) o.h[u] = f2b(a[u]);
                    *reinterpret_cast<int2*>(&Cq[(size_t)grow * 256 + gc]) = o.v;
                } else {
                    if (gc >= 512) {
                        U4 xx; xx.v = *reinterpret_cast<const int2*>(&xg[(size_t)d5 * 256 + (gc - 512)]);
                        #pragma unroll
                        for (int u = 0; u < 4; u++) a[u] += b2f(xx.h[u]);
                    }
                    U4 o;
                    #pragma unroll
                    for (int u = 0; u < 4; u++) o.h[u] = f2b(a[u]);
                    *reinterpret_cast<int2*>(&Ckv[(size_t)grow * 512 + (gc - 256)]) = o.v;
                }
            }
        }
    }
}

// ---------------------------------------------------------------------------
// mgattn: merged node+edge attention (verified r17/r18).
// ---------------------------------------------------------------------------
__global__ __launch_bounds__(256) void mgattn(
    const bf16* __restrict__ QKV, const int* __restrict__ lsrc,
    const bf16* __restrict__ lgx16, bf16* __restrict__ ONo,
    const bf16* __restrict__ QE, const bf16* __restrict__ KVE,
    const int* __restrict__ lgsrc, bf16* __restrict__ OEo,
    int nab)
{
    const int w = threadIdx.x >> 6, lane = threadIdx.x & 63;
    const int c4 = lane * 4;
    if (blockIdx.x < nab) {
        const int d = blockIdx.x * 4 + w;
        if (d >= N_NODES) return;
        U4 uq; uq.v = *reinterpret_cast<const int2*>(&QKV[(size_t)d * 768 + c4]);
        float q[4];
        #pragma unroll
        for (int u = 0; u < 4; u++) q[u] = b2f(uq.h[u]);
        float acc[4] = {0.f, 0.f, 0.f, 0.f};
        float z = 0.f;
        for (int j = 0; j < 16; j++) {
            const int i = d + j * N_NODES;
            const int s = lsrc[i];
            U4 ue; ue.v = *reinterpret_cast<const int2*>(&lgx16[(size_t)i * 256 + c4]);
            U4 uk; uk.v = *reinterpret_cast<const int2*>(&QKV[(size_t)s * 768 + 256 + c4]);
            U4 uv; uv.v = *reinterpret_cast<const int2*>(&QKV[(size_t)s * 768 + 512 + c4]);
            float e[4], p = 0.f;
            #pragma unroll
            for (int u = 0; u < 4; u++) {
                e[u] = b2f(ue.h[u]);
                p += (b2f(uk.h[u]) + e[u]) * q[u];
            }
            p += __shfl_xor(p, 4); p += __shfl_xor(p, 2); p += __shfl_xor(p, 1);
            const float sc = expf(fminf(fmaxf(p * 0.17677669529663687f, -10.f), 10.f));
            #pragma unroll
            for (int u = 0; u < 4; u++) acc[u] += (b2f(uv.h[u]) + e[u]) * sc;
            z += sc;
        }
        U4 o;
        const float iz = 1.f / z;
        #pragma unroll
        for (int u = 0; u < 4; u++) o.h[u] = f2b(acc[u] * iz);
        *reinterpret_cast<int2*>(&ONo[(size_t)d * 256 + c4]) = o.v;
    } else {
        const int b = (blockIdx.x - nab) * 4 + w;
        if (b >= E_EDGES) return;
        U4 uq; uq.v = *reinterpret_cast<const int2*>(&QE[(size_t)b * 256 + c4]);
        float q[4];
        #pragma unroll
        for (int u = 0; u < 4; u++) q[u] = b2f(uq.h[u]);
        float acc[4] = {0.f, 0.f, 0.f, 0.f};
        float z = 0.f;
        #pragma unroll
        for (int j = 0; j < 2; j++) {
            const int s = lgsrc[b + j * E_EDGES];
            const size_t kr = (size_t)s * 512;
            U4 uk; uk.v = *reinterpret_cast<const int2*>(&KVE[kr + c4]);
            U4 uv; uv.v = *reinterpret_cast<const int2*>(&KVE[kr + 256 + c4]);
            float p = 0.f;
            #pragma unroll
            for (int u = 0; u < 4; u++) p += b2f(uk.h[u]) * q[u];
            p += __shfl_xor(p, 4); p += __shfl_xor(p, 2); p += __shfl_xor(p, 1);
            const float sc = expf(fminf(fmaxf(p * 0.17677669529663687f, -10.f), 10.f));
            #pragma unroll
            for (int u = 0; u < 4; u++) acc[u] += b2f(uv.h[u]) * sc;
            z += sc;
        }
        U4 o;
        const float iz = 1.f / z;
        #pragma unroll
        for (int u = 0; u < 4; u++) o.h[u] = f2b(acc[u] * iz);
        *reinterpret_cast<int2*>(&OEo[(size_t)b * 256 + c4]) = o.v;
    }
}

// ---------------------------------------------------------------------------
// mgwoln: merged node+edge Wo+bias+resid -> LN -> bf16 C (verified r17/r18).
// ---------------------------------------------------------------------------
__global__ __launch_bounds__(512) void mgwoln(
    const bf16* __restrict__ An, int Mn,
    const bf16* __restrict__ Ae, int Me,
    const bf16* __restrict__ nBt, const void* __restrict__ nbias,
    const bf16* __restrict__ nresid, const void* __restrict__ nlng, const void* __restrict__ nlnb,
    bf16* __restrict__ Cn,
    const bf16* __restrict__ eBt, const void* __restrict__ ebias,
    const bf16* __restrict__ eresid, const void* __restrict__ elng, const void* __restrict__ elnb,
    bf16* __restrict__ Ce,
    int nby, const int* __restrict__ dflag)
{
    const bool isb = (*dflag != 0);
    __shared__ __align__(16) bf16 Al[128 * 64];   // 16KB (Ps overlay)
    __shared__ __align__(16) bf16 Bl[256 * 64];   // 32KB (Mr/Rsd overlay)
    __shared__ float biasl[256];
    __shared__ float lngl[256];
    __shared__ float lnbl[256];

    const int tid = threadIdx.x;
    const int lane = tid & 63, wave = tid >> 6;
    const int l15 = lane & 15, g = lane >> 4;
    const int t4 = l15 & 3, qd = l15 >> 2;
    const int wr = wave >> 2, wc = wave & 3;   // 2 x 4 wave grid

    const int wg = xcd_swz(blockIdx.y, gridDim.y);
    const bool nodeb = (wg < nby);
    const int rb = (nodeb ? wg : (wg - nby)) * 128;
    const int M = nodeb ? Mn : Me;
    const bf16* A = nodeb ? An : Ae;
    const bf16* Bt = nodeb ? nBt : eBt;
    const void* bias = nodeb ? nbias : ebias;
    const bf16* resid = nodeb ? nresid : eresid;
    const void* lng = nodeb ? nlng : elng;
    const void* lnb = nodeb ? nlnb : elnb;
    bf16* C = nodeb ? Cn : Ce;

    if (tid < 256) {
        biasl[tid] = ldx(bias, tid, isb);
        lngl[tid]  = ldx(lng,  tid, isb);
        lnbl[tid]  = ldx(lnb,  tid, isb);
    }

    const int sp = lane & 7, sr8 = lane >> 3;
    int rlA[2]; long arA[2];
    #pragma unroll
    for (int j = 0; j < 2; j++) {
        const int rl = wave * 16 + j * 8 + sr8;
        rlA[j] = rl;
        const int gm = rb + rl;
        arA[j] = (gm < M) ? gm : (M - 1);
    }
    int rlB[4];
    #pragma unroll
    for (int j = 0; j < 4; j++) rlB[j] = wave * 32 + j * 8 + sr8;

    float4v acc[4][4];
    #pragma unroll
    for (int i = 0; i < 4; i++)
        #pragma unroll
        for (int j = 0; j < 4; j++)
            acc[i][j] = (float4v){0.f, 0.f, 0.f, 0.f};

    for (int k0 = 0; k0 < 256; k0 += 64) {
        #pragma unroll
        for (int j = 0; j < 2; j++) {
            const int pp = sp ^ (rlA[j] & 7);
            gl16(A + arA[j] * 256 + k0 + pp * 8, Al + rlA[j] * 64 + sp * 8);
        }
        #pragma unroll
        for (int j = 0; j < 4; j++) {
            const int pp = sp ^ (rlB[j] & 7);
            gl16(Bt + (size_t)rlB[j] * 256 + k0 + pp * 8, Bl + rlB[j] * 64 + sp * 8);
        }
        __syncthreads();
        #pragma unroll
        for (int ks = 0; ks < 2; ks++) {
            short8v av[4], bv[4];
            #pragma unroll
            for (int mi = 0; mi < 4; mi++) {
                const int row = wr * 64 + mi * 16 + l15;
                const int cp = (ks * 4 + g) ^ (row & 7);
                av[mi] = *reinterpret_cast<const short8v*>(&Al[row * 64 + cp * 8]);
            }
            #pragma unroll
            for (int ni = 0; ni < 4; ni++) {
                const int row = wc * 64 + ni * 16 + l15;
                const int cp = (ks * 4 + g) ^ (row & 7);
                bv[ni] = *reinterpret_cast<const short8v*>(&Bl[row * 64 + cp * 8]);
            }
            #pragma unroll
            for (int mi = 0; mi < 4; mi++)
                #pragma unroll
                for (int ni = 0; ni < 4; ni++)
                    acc[mi][ni] = __builtin_amdgcn_mfma_f32_16x16x32_bf16(
                        av[mi], bv[ni], acc[mi][ni], 0, 0, 0);
        }
        __syncthreads();
    }

    float s1[4] = {0.f,0.f,0.f,0.f}, s2[4] = {0.f,0.f,0.f,0.f};
    #pragma unroll
    for (int mi = 0; mi < 4; mi++) {
        const int grow = rb + wr * 64 + mi * 16 + g * 4 + t4;
        const bool ok = (grow < M);
        #pragma unroll
        for (int ni = 0; ni < 4; ni++) {
            float a[4];
            #pragma unroll
            for (int r = 0; r < 4; r++) a[r] = acc[mi][ni][r];
            quadT(a, t4);
            const int ct = wc * 64 + ni * 16 + qd * 4;
            U4 rr; rr.v = make_int2(0, 0);
            if (ok) rr.v = *reinterpret_cast<const int2*>(&resid[(size_t)grow * 256 + ct]);
            #pragma unroll
            for (int u = 0; u < 4; u++) {
                a[u] += biasl[ct + u] + b2f(rr.h[u]);
                s1[mi] += a[u];
                s2[mi] += a[u] * a[u];
                acc[mi][ni][u] = a[u];
            }
        }
    }
    float* Ps1 = (float*)Al;          // [16][128]
    float* Ps2 = Ps1 + 2048;
    #pragma unroll
    for (int mi = 0; mi < 4; mi++) {
        const int rowl = wr * 64 + mi * 16 + g * 4 + t4;
        Ps1[(wc * 4 + qd) * 128 + rowl] = s1[mi];
        Ps2[(wc * 4 + qd) * 128 + rowl] = s2[mi];
    }
    __syncthreads();
    float* Mr  = (float*)Bl;
    float* Rsd = Mr + 128;
    if (tid < 128) {
        float a1 = 0.f, a2 = 0.f;
        #pragma unroll
        for (int k = 0; k < 16; k++) { a1 += Ps1[k * 128 + tid]; a2 += Ps2[k * 128 + tid]; }
        const float mn = a1 * (1.f / 256.f);
        const float var = a2 * (1.f / 256.f) - mn * mn;
        Mr[tid] = mn;
        Rsd[tid] = rsqrtf(fmaxf(var, 0.f) + 1e-5f);
    }
    __syncthreads();
    #pragma unroll
    for (int mi = 0; mi < 4; mi++) {
        const int rowl = wr * 64 + mi * 16 + g * 4 + t4;
        const int grow = rb + rowl;
        if (grow >= M) continue;
        const float mn = Mr[rowl], rd = Rsd[rowl];
        #pragma unroll
        for (int ni = 0; ni < 4; ni++) {
            const int ct = wc * 64 + ni * 16 + qd * 4;
            U4 ob;
            #pragma unroll
            for (int u = 0; u < 4; u++)
                ob.h[u] = f2b((acc[mi][ni][u] - mn) * rd * lngl[ct + u] + lnbl[ct + u]);
            *reinterpret_cast<int2*>(&C[(size_t)grow * 256 + ct]) = ob.v;
        }
    }
}

// ---------------------------------------------------------------------------
// mgffn1: merged node+edge FFN1 relu(+bias), K=256, NC=1024 (verified r17/r18).
// ---------------------------------------------------------------------------
__global__ __launch_bounds__(256) void mgffn1(
    const bf16* __restrict__ An, int Mn,
    const bf16* __restrict__ Ae, int Me,
    const bf16* __restrict__ nBt, const void* __restrict__ nbias, bf16* __restrict__ Cn,
    const bf16* __restrict__ eBt, const void* __restrict__ ebias, bf16* __restrict__ Ce,
    int nby, const int* __restrict__ dflag)
{
    const bool isb = (*dflag != 0);
    __shared__ __align__(16) bf16 Al[128 * 64];
    __shared__ __align__(16) bf16 Bl[128 * 64];
    __shared__ float biasl[128];

    const int tid = threadIdx.x;
    const int lane = tid & 63, wave = tid >> 6;
    const int l15 = lane & 15, g = lane >> 4;
    const int t4 = l15 & 3, qd = l15 >> 2;
    const int wr = wave >> 1, wc = wave & 1;

    const int nwgx = gridDim.x;   // 8
    int wg = xcd_swz(blockIdx.y * nwgx + blockIdx.x, nwgx * gridDim.y);
    const int by = wg / nwgx, bx = wg % nwgx;
    const bool nodeb = (by < nby);
    const int rb = (nodeb ? by : (by - nby)) * 128;
    const int cb = bx * 128;
    const int M = nodeb ? Mn : Me;
    const bf16* A = nodeb ? An : Ae;
    const bf16* Bt = nodeb ? nBt : eBt;
    const void* bias = nodeb ? nbias : ebias;
    bf16* C = nodeb ? Cn : Ce;

    if (tid < 128) biasl[tid] = ldx(bias, cb + tid, isb);

    const int sp = lane & 7, sr8 = lane >> 3;
    int rls[4]; long arows[4];
    #pragma unroll
    for (int j = 0; j < 4; j++) {
        const int rl = wave * 32 + j * 8 + sr8;
        rls[j] = rl;
        const int gm = rb + rl;
        arows[j] = (gm < M) ? gm : (M - 1);
    }

    float4v acc[4][4];
    #pragma unroll
    for (int i = 0; i < 4; i++)
        #pragma unroll
        for (int j = 0; j < 4; j++)
            acc[i][j] = (float4v){0.f, 0.f, 0.f, 0.f};

    for (int k0 = 0; k0 < 256; k0 += 64) {
        #pragma unroll
        for (int j = 0; j < 4; j++) {
            const int rl = rls[j];
            const int pp = sp ^ (rl & 7);
            gl16(A + arows[j] * 256 + k0 + pp * 8,              Al + rl * 64 + sp * 8);
            gl16(Bt + (size_t)(cb + rl) * 256 + k0 + pp * 8,    Bl + rl * 64 + sp * 8);
        }
        __syncthreads();
        #pragma unroll
        for (int ks = 0; ks < 2; ks++) {
            short8v av[4], bv[4];
            #pragma unroll
            for (int mi = 0; mi < 4; mi++) {
                const int row = wr * 64 + mi * 16 + l15;
                const int cp = (ks * 4 + g) ^ (row & 7);
                av[mi] = *reinterpret_cast<const short8v*>(&Al[row * 64 + cp * 8]);
            }
            #pragma unroll
            for (int ni = 0; ni < 4; ni++) {
                const int row = wc * 64 + ni * 16 + l15;
                const int cp = (ks * 4 + g) ^ (row & 7);
                bv[ni] = *reinterpret_cast<const short8v*>(&Bl[row * 64 + cp * 8]);
            }
            #pragma unroll
            for (int mi = 0; mi < 4; mi++)
                #pragma unroll
                for (int ni = 0; ni < 4; ni++)
                    acc[mi][ni] = __builtin_amdgcn_mfma_f32_16x16x32_bf16(
                        av[mi], bv[ni], acc[mi][ni], 0, 0, 0);
        }
        __syncthreads();
    }

    #pragma unroll
    for (int mi = 0; mi < 4; mi++) {
        const int grow = rb + wr * 64 + mi * 16 + g * 4 + t4;
        const bool ok = (grow < M);
        #pragma unroll
        for (int ni = 0; ni < 4; ni++) {
            float a[4];
            #pragma unroll
            for (int r = 0; r < 4; r++) a[r] = acc[mi][ni][r];
            quadT(a, t4);
            if (!ok) continue;
            const int ct = wc * 64 + ni * 16 + qd * 4;
            U4 o;
            #pragma unroll
            for (int u = 0; u < 4; u++) o.h[u] = f2b(fmaxf(a[u] + biasl[ct + u], 0.f));
            *reinterpret_cast<int2*>(&C[(size_t)grow * 1024 + cb + ct]) = o.v;
        }
    }
}

// ---------------------------------------------------------------------------
// mgffn2: merged node+edge FFN2(+bias+resid) -> LN -> dtype-flex out
// (verified r17/r18).  512 thr, K=1024.
// ---------------------------------------------------------------------------
__global__ __launch_bounds__(512) void mgffn2(
    const bf16* __restrict__ An, int Mn,
    const bf16* __restrict__ Ae, int Me,
    const bf16* __restrict__ nBt, const void* __restrict__ nbias,
    const bf16* __restrict__ nresid, const void* __restrict__ nlng, const void* __restrict__ nlnb,
    long nobase,
    const bf16* __restrict__ eBt, const void* __restrict__ ebias,
    const bf16* __restrict__ eresid, const void* __restrict__ elng, const void* __restrict__ elnb,
    long eobase,
    void* __restrict__ outv,
    int nby, const int* __restrict__ dflag)
{
    const bool isb = (*dflag != 0);
    __shared__ __align__(16) bf16 Al[128 * 64];   // 16KB (Ps overlay)
    __shared__ __align__(16) bf16 Bl[256 * 64];   // 32KB (Mr/Rsd overlay)
    __shared__ float biasl[256];
    __shared__ float lngl[256];
    __shared__ float lnbl[256];

    const int tid = threadIdx.x;
    const int lane = tid & 63, wave = tid >> 6;
    const int l15 = lane & 15, g = lane >> 4;
    const int t4 = l15 & 3, qd = l15 >> 2;
    const int wr = wave >> 2, wc = wave & 3;   // 2 x 4 wave grid

    const int wg = xcd_swz(blockIdx.y, gridDim.y);
    const bool nodeb = (wg < nby);
    const int rb = (nodeb ? wg : (wg - nby)) * 128;
    const int M = nodeb ? Mn : Me;
    const bf16* A = nodeb ? An : Ae;
    const bf16* Bt = nodeb ? nBt : eBt;
    const void* bias = nodeb ? nbias : ebias;
    const bf16* resid = nodeb ? nresid : eresid;
    const void* lng = nodeb ? nlng : elng;
    const void* lnb = nodeb ? nlnb : elnb;
    const long obase = nodeb ? nobase : eobase;

    if (tid < 256) {
        biasl[tid] = ldx(bias, tid, isb);
        lngl[tid]  = ldx(lng,  tid, isb);
        lnbl[tid]  = ldx(lnb,  tid, isb);
    }

    const int sp = lane & 7, sr8 = lane >> 3;
    int rlA[2]; long arA[2];
    #pragma unroll
    for (int j = 0; j < 2; j++) {
        const int rl = wave * 16 + j * 8 + sr8;
        rlA[j] = rl;
        const int gm = rb + rl;
        arA[j] = (gm < M) ? gm : (M - 1);
    }
    int rlB[4];
    #pragma unroll
    for (int j = 0; j < 4; j++) rlB[j] = wave * 32 + j * 8 + sr8;

    float4v acc[4][4];
    #pragma unroll
    for (int i = 0; i < 4; i++)
        #pragma unroll
        for (int j = 0; j < 4; j++)
            acc[i][j] = (float4v){0.f, 0.f, 0.f, 0.f};

    for (int k0 = 0; k0 < 1024; k0 += 64) {
        #pragma unroll
        for (int j = 0; j < 2; j++) {
            const int pp = sp ^ (rlA[j] & 7);
            gl16(A + arA[j] * 1024 + k0 + pp * 8, Al + rlA[j] * 64 + sp * 8);
        }
        #pragma unroll
        for (int j = 0; j < 4; j++) {
            const int pp = sp ^ (rlB[j] & 7);
            gl16(Bt + (size_t)rlB[j] * 1024 + k0 + pp * 8, Bl + rlB[j] * 64 + sp * 8);
        }
        __syncthreads();
        #pragma unroll
        for (int ks = 0; ks < 2; ks++) {
            short8v av[4], bv[4];
            #pragma unroll
            for (int mi = 0; mi < 4; mi++) {
                const int row = wr * 64 + mi * 16 + l15;
                const int cp = (ks * 4 + g) ^ (row & 7);
                av[mi] = *reinterpret_cast<const short8v*>(&Al[row * 64 + cp * 8]);
            }
            #pragma unroll
            for (int ni = 0; ni < 4; ni++) {
                const int row = wc * 64 + ni * 16 + l15;
                const int cp = (ks * 4 + g) ^ (row & 7);
                bv[ni] = *reinterpret_cast<const short8v*>(&Bl[row * 64 + cp * 8]);
            }
            #pragma unroll
            for (int mi = 0; mi < 4; mi++)
                #pragma unroll
                for (int ni = 0; ni < 4; ni++)
                    acc[mi][ni] = __builtin_amdgcn_mfma_f32_16x16x32_bf16(
                        av[mi], bv[ni], acc[mi][ni], 0, 0, 0);
        }
        __syncthreads();
    }

    float s1[4] = {0.f,0.f,0.f,0.f}, s2[4] = {0.f,0.f,0.f,0.f};
    #pragma unroll
    for (int mi = 0; mi < 4; mi++) {
        const int grow = rb + wr * 64 + mi * 16 + g * 4 + t4;
        const bool ok = (grow < M);
        #pragma unroll
        for (int ni = 0; ni < 4; ni++) {
            float a[4];
            #pragma unroll
            for (int r = 0; r < 4; r++) a[r] = acc[mi][ni][r];
            quadT(a, t4);
            const int ct = wc * 64 + ni * 16 + qd * 4;
            U4 rr; rr.v = make_int2(0, 0);
            if (ok) rr.v = *reinterpret_cast<const int2*>(&resid[(size_t)grow * 256 + ct]);
            #pragma unroll
            for (int u = 0; u < 4; u++) {
                a[u] += biasl[ct + u] + b2f(rr.h[u]);
                s1[mi] += a[u];
                s2[mi] += a[u] * a[u];
                acc[mi][ni][u] = a[u];
            }
        }
    }
    float* Ps1 = (float*)Al;          // [16][128]
    float* Ps2 = Ps1 + 2048;
    #pragma unroll
    for (int mi = 0; mi < 4; mi++) {
        const int rowl = wr * 64 + mi * 16 + g * 4 + t4;
        Ps1[(wc * 4 + qd) * 128 + rowl] = s1[mi];
        Ps2[(wc * 4 + qd) * 128 + rowl] = s2[mi];
    }
    __syncthreads();
    float* Mr  = (float*)Bl;
    float* Rsd = Mr + 128;
    if (tid < 128) {
        float a1 = 0.f, a2 = 0.f;
        #pragma unroll
        for (int k = 0; k < 16; k++) { a1 += Ps1[k * 128 + tid]; a2 += Ps2[k * 128 + tid]; }
        const float mn = a1 * (1.f / 256.f);
        const float var = a2 * (1.f / 256.f) - mn * mn;
        Mr[tid] = mn;
        Rsd[tid] = rsqrtf(fmaxf(var, 0.f) + 1e-5f);
    }
    __syncthreads();
    #pragma unroll
    for (int mi = 0; mi < 4; mi++) {
        const int rowl = wr * 64 + mi * 16 + g * 4 + t4;
        const int grow = rb + rowl;
        if (grow >= M) continue;
        const float mn = Mr[rowl], rd = Rsd[rowl];
        #pragma unroll
        for (int ni = 0; ni < 4; ni++) {
            const int ct = wc * 64 + ni * 16 + qd * 4;
            float o[4];
            #pragma unroll
            for (int u = 0; u < 4; u++)
                o[u] = (acc[mi][ni][u] - mn) * rd * lngl[ct + u] + lnbl[ct + u];
            if (isb) {
                U4 ob;
                #pragma unroll
                for (int u = 0; u < 4; u++) ob.h[u] = f2b(o[u]);
                *reinterpret_cast<int2*>((bf16*)outv + obase + (size_t)grow * 256 + ct) = ob.v;
            } else {
                float4 f4 = make_float4(o[0], o[1], o[2], o[3]);
                *reinterpret_cast<float4*>((float*)outv + obase + (size_t)grow * 256 + ct) = f4;
            }
        }
    }
}

// ---------------------------------------------------------------------------
extern "C" void kernel_launch(void* const* d_in, const int* in_sizes, int n_in,
                              void* d_out, int out_size, void* d_ws, size_t ws_size,
                              hipStream_t stream)
{
    const void* x   = d_in[0];
    const void* lgx = d_in[1];
    const int* local_src = (const int*)d_in[3];
    const int* lg_src    = (const int*)d_in[5];
    const int* src_ids   = (const int*)d_in[7];
    const int* dst_ids   = (const int*)d_in[8];

    const void *nWq = d_in[9],  *nbq = d_in[10], *nWk = d_in[11], *nWv = d_in[12],
               *nWo = d_in[13], *nbo = d_in[14], *nln1g = d_in[15], *nln1b = d_in[16],
               *nW1 = d_in[17], *nb1 = d_in[18], *nW2 = d_in[19], *nb2 = d_in[20],
               *nln2g = d_in[21], *nln2b = d_in[22];
    const void *eWq = d_in[23], *ebq = d_in[24], *eWk = d_in[25], *eWv = d_in[26],
               *eWo = d_in[27], *ebo = d_in[28], *eln1g = d_in[29], *eln1b = d_in[30],
               *eW1 = d_in[31], *eb1 = d_in[32], *eW2 = d_in[33], *eb2 = d_in[34],
               *eln2g = d_in[35], *eln2b = d_in[36];

    const dim3 blk(256);
    const dim3 blk2(512);

    // ===== ws layout (elements, bf16).  FE overlays [KVE..OE) which is dead
    // by the time mgffn1 runs.  fixed total = 545.9 MB < ~696 MB measured.
    int* dflag = (int*)d_ws;
    detect_dtype<<<1, 64, 0, stream>>>((const unsigned short*)x, dflag);

    bf16* pk = (bf16*)((char*)d_ws + 256);
    bf16 *pnWq = pk,            *pnWk = pk + 65536,   *pnWv = pk + 131072,
         *pnWo = pk + 196608,   *peWq = pk + 262144,  *peWk = pk + 327680,
         *peWv = pk + 393216,   *peWo = pk + 458752,
         *pnW1 = pk + 524288,   *pnW2 = pk + 786432,
         *peW1 = pk + 1048576,  *peW2 = pk + 1310720;
    bf16* x16   = pk + 1572864;                        //  2,560,000 elems
    bf16* lgx16 = x16 + 2560000;                       // 40,960,000
    bf16* KVE   = lgx16 + 40960000;                    // 81,920,000  (overlay start)
    bf16* QE    = KVE + 81920000;                      // 40,960,000
    bf16* QKVN  = QE + 40960000;                       //  7,680,000
    bf16* OE    = QKVN + 7680000;                      // 40,960,000  (overlay end: 171.52M elems)
    bf16* ON    = OE + 40960000;                       //  2,560,000
    bf16* HN    = ON + 2560000;                        //  2,560,000
    bf16* FN    = HN + 2560000;                        // 10,240,000
    bf16* HE    = FN + 10240000;                       // 40,960,000
    bf16* FE    = KVE;                                 // overlay: 163,840,000 <= 171,520,000

    cvt_both<<<21250, blk, 0, stream>>>(x, lgx, x16, lgx16, dflag);

    PackArgs pa;
    pa.src[0] = nWq; pa.src[1] = nWk; pa.src[2] = nWv; pa.src[3] = nWo;
    pa.src[4] = eWq; pa.src[5] = eWk; pa.src[6] = eWv; pa.src[7] = eWo;
    pa.src[8] = nW1; pa.src[9] = nW2; pa.src[10] = eW1; pa.src[11] = eW2;
    pa.dst[0] = pnWq; pa.dst[1] = pnWk; pa.dst[2] = pnWv; pa.dst[3] = pnWo;
    pa.dst[4] = peWq; pa.dst[5] = peWk; pa.dst[6] = peWv; pa.dst[7] = peWo;
    pa.dst[8] = pnW1; pa.dst[9] = pnW2; pa.dst[10] = peW1; pa.dst[11] = peW2;
    pack_all<<<6144, blk, 0, stream>>>(pa, dflag);

    const int nby = (N_NODES + 127) / 128;   // 79
    const int eby = (E_EDGES + 127) / 128;   // 1250

    // stage 1: merged QKV (node + edge)
    mgqkv<<<dim3(6, nby + eby), blk, 0, stream>>>(
        x16, N_NODES, lgx16, E_EDGES,
        pnWq, pnWk, pnWv, nbq,
        peWq, peWk, peWv, ebq,
        x16, src_ids, dst_ids,
        QKVN, QE, KVE, nby, dflag);

    // stage 2: merged attention
    const int nab = (N_NODES + 3) / 4;        // 2500
    const int eab = (E_EDGES + 3) / 4;        // 40000
    mgattn<<<nab + eab, blk, 0, stream>>>(
        QKVN, local_src, lgx16, ON, QE, KVE, lg_src, OE, nab);

    // stage 3: merged Wo + LN1
    mgwoln<<<dim3(1, nby + eby), blk2, 0, stream>>>(
        ON, N_NODES, OE, E_EDGES,
        pnWo, nbo, x16, nln1g, nln1b, HN,
        peWo, ebo, lgx16, eln1g, eln1b, HE,
        nby, dflag);

    // stage 4: merged FFN1 (full E, FE overlays dead buffers)
    mgffn1<<<dim3(8, nby + eby), blk, 0, stream>>>(
        HN, N_NODES, HE, E_EDGES,
        pnW1, nb1, FN,
        peW1, eb1, FE,
        nby, dflag);

    // stage 5: merged FFN2 + LN2 -> out
    mgffn2<<<dim3(1, nby + eby), blk2, 0, stream>>>(
        FN, N_NODES, FE, E_EDGES,
        pnW2, nb2, HN, nln2g, nln2b, 0L,
        peW2, eb2, HE, eln2g, eln2b, (long)N_NODES * 256,
        d_out, nby, dflag);
}

// Round 21
// 951.810 us; speedup vs baseline: 1.0677x; 1.0043x over previous
//
#include <hip/hip_runtime.h>
#include <hip/hip_bf16.h>

typedef __hip_bfloat16 bf16;
typedef __attribute__((ext_vector_type(8))) short short8v;
typedef __attribute__((ext_vector_type(4))) float float4v;

#define N_NODES 10000
#define E_EDGES 160000

__device__ __forceinline__ float b2f(bf16 v){ return __bfloat162float(v); }
__device__ __forceinline__ bf16 f2b(float v){ return __float2bfloat16(v); }

union U8 { int4 v; bf16 h[8]; };
union U4 { int2 v; bf16 h[4]; };

// ---- dtype-flexible external accessors (flag: 1 = bf16, 0 = f32) ----------
__device__ __forceinline__ float ldx(const void* p, size_t i, bool isb){
    return isb ? b2f(((const bf16*)p)[i]) : ((const float*)p)[i];
}
__device__ __forceinline__ void ld8(const void* p, size_t i, bool isb, float* o){
    if (isb) {
        U8 u; u.v = *reinterpret_cast<const int4*>((const bf16*)p + i);
        #pragma unroll
        for (int j = 0; j < 8; j++) o[j] = b2f(u.h[j]);
    } else {
        const float4* q = reinterpret_cast<const float4*>((const float*)p + i);
        float4 a = q[0], b = q[1];
        o[0]=a.x; o[1]=a.y; o[2]=a.z; o[3]=a.w; o[4]=b.x; o[5]=b.y; o[6]=b.z; o[7]=b.w;
    }
}
__device__ __forceinline__ void stx(void* p, size_t i, bool isb, float v){
    if (isb) ((bf16*)p)[i] = f2b(v); else ((float*)p)[i] = v;
}

// async global->LDS, 16 B/lane (HW: LDS dest = wave-uniform base + lane*16)
typedef const __attribute__((address_space(1))) void* gas_p;
typedef __attribute__((address_space(3))) void* las_p;
__device__ __forceinline__ void gl16(const bf16* g, bf16* l){
    __builtin_amdgcn_global_load_lds((gas_p)g, (las_p)l, 16, 0, 0);
}

// 4x4 in-register transpose across 4 lanes (verified r9-r20)
__device__ __forceinline__ void quadT(float* a, int t){
    float x0 = (t & 1) ? a[0] : a[1];
    float y0 = __shfl_xor(x0, 1);
    if (t & 1) a[0] = y0; else a[1] = y0;
    float x1 = (t & 1) ? a[2] : a[3];
    float y1 = __shfl_xor(x1, 1);
    if (t & 1) a[2] = y1; else a[3] = y1;
    float x2 = (t & 2) ? a[0] : a[2];
    float y2 = __shfl_xor(x2, 2);
    if (t & 2) a[0] = y2; else a[2] = y2;
    float x3 = (t & 2) ? a[1] : a[3];
    float y3 = __shfl_xor(x3, 2);
    if (t & 2) a[1] = y3; else a[3] = y3;
}

// XCD-bijective swizzle of a linear workgroup id
__device__ __forceinline__ int xcd_swz(int wg, int nwg){
    const int q = nwg >> 3, r = nwg & 7;
    const int xcd = wg & 7, ix = wg >> 3;
    return (xcd < r ? xcd * (q + 1) : r * (q + 1) + (xcd - r) * q) + ix;
}

// ---------------------------------------------------------------------------
__global__ void detect_dtype(const unsigned short* __restrict__ xw, int* __restrict__ flag){
    const int lane = threadIdx.x;  // 64 threads
    int cnt = 0;
    for (int i = lane; i < 8192; i += 64) {
        const unsigned e = (xw[i] >> 7) & 0xFF;
        if (e == 0 || (e >= 100 && e <= 140)) cnt++;
    }
    #pragma unroll
    for (int off = 32; off >= 1; off >>= 1) cnt += __shfl_xor(cnt, off);
    if (lane == 0) *flag = (cnt >= 6554) ? 1 : 0;
}

// merged convert: groups [0, 320000) -> x16; [320000, 5440000) -> lgx16
__global__ __launch_bounds__(256) void cvt_both(
    const void* __restrict__ xin, const void* __restrict__ lgin,
    bf16* __restrict__ x16, bf16* __restrict__ lgx16,
    const int* __restrict__ dflag)
{
    const bool isb = (*dflag != 0);
    const long t = (long)blockIdx.x * 256 + threadIdx.x;
    if (t >= 5440000L) return;
    float f[8];
    if (t < 320000L) {
        ld8(xin, (size_t)t * 8, isb, f);
        U8 u;
        #pragma unroll
        for (int j = 0; j < 8; j++) u.h[j] = f2b(f[j]);
        *reinterpret_cast<int4*>(&x16[t * 8]) = u.v;
    } else {
        const long s = t - 320000L;
        ld8(lgin, (size_t)s * 8, isb, f);
        U8 u;
        #pragma unroll
        for (int j = 0; j < 8; j++) u.h[j] = f2b(f[j]);
        *reinterpret_cast<int4*>(&lgx16[s * 8]) = u.v;
    }
}

// ---------------------------------------------------------------------------
// pack_all: all 12 weight matrices -> transposed bf16 [Nmat][K] in one launch.
// ---------------------------------------------------------------------------
struct PackArgs { const void* src[12]; bf16* dst[12]; };
__global__ __launch_bounds__(256) void pack_all(PackArgs pa, const int* __restrict__ dflag){
    const bool isb = (*dflag != 0);
    const long idx = (long)blockIdx.x * 256 + threadIdx.x;
    if (idx >= 1572864) return;
    int m, local, K, Nmat;
    if (idx < 524288) { m = (int)(idx >> 16); local = (int)(idx & 65535); K = 256; Nmat = 256; }
    else {
        const long j = idx - 524288;
        const int m2 = (int)(j >> 18); local = (int)(j & 262143);
        m = 8 + m2;
        if (m2 == 0 || m2 == 2) { K = 256; Nmat = 1024; } else { K = 1024; Nmat = 256; }
    }
    const int k = local / Nmat, n = local - k * Nmat;
    pa.dst[m][(size_t)n * K + k] = f2b(ldx(pa.src[m], local, isb));
}

// ---------------------------------------------------------------------------
// mgqkv: merged node-QKV + edge-QKV (verified r17-r20).
// ---------------------------------------------------------------------------
__global__ __launch_bounds__(256) void mgqkv(
    const bf16* __restrict__ An, int Mn,
    const bf16* __restrict__ Ae, int Me,
    const bf16* __restrict__ nBq, const bf16* __restrict__ nBk, const bf16* __restrict__ nBv,
    const void* __restrict__ nbias,
    const bf16* __restrict__ eBq, const bf16* __restrict__ eBk, const bf16* __restrict__ eBv,
    const void* __restrict__ ebias,
    const bf16* __restrict__ xg,
    const int* __restrict__ sidx, const int* __restrict__ didx,
    bf16* __restrict__ Cn, bf16* __restrict__ Cq, bf16* __restrict__ Ckv,
    int nby, const int* __restrict__ dflag)
{
    const bool isb = (*dflag != 0);
    __shared__ __align__(16) bf16 Al[128 * 64];
    __shared__ __align__(16) bf16 Bl[128 * 64];
    __shared__ float biasl[128];

    const int tid = threadIdx.x;
    const int lane = tid & 63, wave = tid >> 6;
    const int l15 = lane & 15, g = lane >> 4;
    const int t4 = l15 & 3, qd = l15 >> 2;
    const int wr = wave >> 1, wc = wave & 1;

    const int nwgx = gridDim.x;
    int wg = xcd_swz(blockIdx.y * nwgx + blockIdx.x, nwgx * gridDim.y);
    const int by = wg / nwgx, bx = wg % nwgx;
    const bool nodeb = (by < nby);
    const int rb = (nodeb ? by : (by - nby)) * 128;
    const int cb = bx * 128;
    const int M = nodeb ? Mn : Me;
    const bf16* A = nodeb ? An : Ae;
    const int seg = cb >> 8;
    const bf16* Bsel = nodeb ? ((seg == 0) ? nBq : ((seg == 1) ? nBk : nBv))
                             : ((seg == 0) ? eBq : ((seg == 1) ? eBk : eBv));
    const void* bias = nodeb ? nbias : ebias;
    const int cloc = cb & 255;

    if (tid < 128) {
        const int gc = cb + tid;
        biasl[tid] = (gc < 256) ? ldx(bias, gc, isb) : 0.f;
    }

    const int sp = lane & 7, sr8 = lane >> 3;
    int rls[4]; long arows[4];
    #pragma unroll
    for (int j = 0; j < 4; j++) {
        const int rl = wave * 32 + j * 8 + sr8;
        rls[j] = rl;
        const int gm = rb + rl;
        arows[j] = (gm < M) ? gm : (M - 1);
    }

    float4v acc[4][4];
    #pragma unroll
    for (int i = 0; i < 4; i++)
        #pragma unroll
        for (int j = 0; j < 4; j++)
            acc[i][j] = (float4v){0.f, 0.f, 0.f, 0.f};

    for (int k0 = 0; k0 < 256; k0 += 64) {
        #pragma unroll
        for (int j = 0; j < 4; j++) {
            const int rl = rls[j];
            const int pp = sp ^ (rl & 7);
            gl16(A + arows[j] * 256 + k0 + pp * 8,                 Al + rl * 64 + sp * 8);
            gl16(Bsel + (size_t)(cloc + rl) * 256 + k0 + pp * 8,   Bl + rl * 64 + sp * 8);
        }
        __syncthreads();
        #pragma unroll
        for (int ks = 0; ks < 2; ks++) {
            short8v av[4], bv[4];
            #pragma unroll
            for (int mi = 0; mi < 4; mi++) {
                const int row = wr * 64 + mi * 16 + l15;
                const int cp = (ks * 4 + g) ^ (row & 7);
                av[mi] = *reinterpret_cast<const short8v*>(&Al[row * 64 + cp * 8]);
            }
            #pragma unroll
            for (int ni = 0; ni < 4; ni++) {
                const int row = wc * 64 + ni * 16 + l15;
                const int cp = (ks * 4 + g) ^ (row & 7);
                bv[ni] = *reinterpret_cast<const short8v*>(&Bl[row * 64 + cp * 8]);
            }
            #pragma unroll
            for (int mi = 0; mi < 4; mi++)
                #pragma unroll
                for (int ni = 0; ni < 4; ni++)
                    acc[mi][ni] = __builtin_amdgcn_mfma_f32_16x16x32_bf16(
                        av[mi], bv[ni], acc[mi][ni], 0, 0, 0);
        }
        __syncthreads();
    }

    #pragma unroll
    for (int mi = 0; mi < 4; mi++) {
        const int grow = rb + wr * 64 + mi * 16 + g * 4 + t4;
        const bool ok = (grow < M);
        int s5 = 0, d5 = 0;
        if (!nodeb && ok) {
            if (cb < 256) s5 = sidx[grow];
            else if (cb >= 512) d5 = didx[grow];
        }
        #pragma unroll
        for (int ni = 0; ni < 4; ni++) {
            float a[4];
            #pragma unroll
            for (int r = 0; r < 4; r++) a[r] = acc[mi][ni][r];
            quadT(a, t4);
            if (!ok) continue;
            const int ct = wc * 64 + ni * 16 + qd * 4;
            const int gc = cb + ct;
            if (nodeb) {
                if (gc < 256) {
                    #pragma unroll
                    for (int u = 0; u < 4; u++) a[u] += biasl[ct + u];
                }
                U4 o;
                #pragma unroll
                for (int u = 0; u < 4; u++) o.h[u] = f2b(a[u]);
                *reinterpret_cast<int2*>(&Cn[(size_t)grow * 768 + gc]) = o.v;
            } else {
                if (gc < 256) {
                    U4 xx; xx.v = *reinterpret_cast<const int2*>(&xg[(size_t)s5 * 256 + gc]);
                    #pragma unroll
                    for (int u = 0; u < 4; u++) a[u] += biasl[ct + u] + b2f(xx.h[u]);
                    U4 o;
                    #pragma unroll
                    for (int u = 0; u < 4; u++) o.h[u] = f2b(a[u]);
                    *reinterpret_cast<int2*>(&Cq[(size_t)grow * 256 + gc]) = o.v;
                } else {
                    if (gc >= 512) {
                        U4 xx; xx.v = *reinterpret_cast<const int2*>(&xg[(size_t)d5 * 256 + (gc - 512)]);
                        #pragma unroll
                        for (int u = 0; u < 4; u++) a[u] += b2f(xx.h[u]);
                    }
                    U4 o;
                    #pragma unroll
                    for (int u = 0; u < 4; u++) o.h[u] = f2b(a[u]);
                    *reinterpret_cast<int2*>(&Ckv[(size_t)grow * 512 + (gc - 256)]) = o.v;
                }
            }
        }
    }
}

// ---------------------------------------------------------------------------
// mgattn: merged node+edge attention (verified r17-r20).
// ---------------------------------------------------------------------------
__global__ __launch_bounds__(256) void mgattn(
    const bf16* __restrict__ QKV, const int* __restrict__ lsrc,
    const bf16* __restrict__ lgx16, bf16* __restrict__ ONo,
    const bf16* __restrict__ QE, const bf16* __restrict__ KVE,
    const int* __restrict__ lgsrc, bf16* __restrict__ OEo,
    int nab)
{
    const int w = threadIdx.x >> 6, lane = threadIdx.x & 63;
    const int c4 = lane * 4;
    if (blockIdx.x < nab) {
        const int d = blockIdx.x * 4 + w;
        if (d >= N_NODES) return;
        U4 uq; uq.v = *reinterpret_cast<const int2*>(&QKV[(size_t)d * 768 + c4]);
        float q[4];
        #pragma unroll
        for (int u = 0; u < 4; u++) q[u] = b2f(uq.h[u]);
        float acc[4] = {0.f, 0.f, 0.f, 0.f};
        float z = 0.f;
        for (int j = 0; j < 16; j++) {
            const int i = d + j * N_NODES;
            const int s = lsrc[i];
            U4 ue; ue.v = *reinterpret_cast<const int2*>(&lgx16[(size_t)i * 256 + c4]);
            U4 uk; uk.v = *reinterpret_cast<const int2*>(&QKV[(size_t)s * 768 + 256 + c4]);
            U4 uv; uv.v = *reinterpret_cast<const int2*>(&QKV[(size_t)s * 768 + 512 + c4]);
            float e[4], p = 0.f;
            #pragma unroll
            for (int u = 0; u < 4; u++) {
                e[u] = b2f(ue.h[u]);
                p += (b2f(uk.h[u]) + e[u]) * q[u];
            }
            p += __shfl_xor(p, 4); p += __shfl_xor(p, 2); p += __shfl_xor(p, 1);
            const float sc = expf(fminf(fmaxf(p * 0.17677669529663687f, -10.f), 10.f));
            #pragma unroll
            for (int u = 0; u < 4; u++) acc[u] += (b2f(uv.h[u]) + e[u]) * sc;
            z += sc;
        }
        U4 o;
        const float iz = 1.f / z;
        #pragma unroll
        for (int u = 0; u < 4; u++) o.h[u] = f2b(acc[u] * iz);
        *reinterpret_cast<int2*>(&ONo[(size_t)d * 256 + c4]) = o.v;
    } else {
        const int b = (blockIdx.x - nab) * 4 + w;
        if (b >= E_EDGES) return;
        U4 uq; uq.v = *reinterpret_cast<const int2*>(&QE[(size_t)b * 256 + c4]);
        float q[4];
        #pragma unroll
        for (int u = 0; u < 4; u++) q[u] = b2f(uq.h[u]);
        float acc[4] = {0.f, 0.f, 0.f, 0.f};
        float z = 0.f;
        #pragma unroll
        for (int j = 0; j < 2; j++) {
            const int s = lgsrc[b + j * E_EDGES];
            const size_t kr = (size_t)s * 512;
            U4 uk; uk.v = *reinterpret_cast<const int2*>(&KVE[kr + c4]);
            U4 uv; uv.v = *reinterpret_cast<const int2*>(&KVE[kr + 256 + c4]);
            float p = 0.f;
            #pragma unroll
            for (int u = 0; u < 4; u++) p += b2f(uk.h[u]) * q[u];
            p += __shfl_xor(p, 4); p += __shfl_xor(p, 2); p += __shfl_xor(p, 1);
            const float sc = expf(fminf(fmaxf(p * 0.17677669529663687f, -10.f), 10.f));
            #pragma unroll
            for (int u = 0; u < 4; u++) acc[u] += b2f(uv.h[u]) * sc;
            z += sc;
        }
        U4 o;
        const float iz = 1.f / z;
        #pragma unroll
        for (int u = 0; u < 4; u++) o.h[u] = f2b(acc[u] * iz);
        *reinterpret_cast<int2*>(&OEo[(size_t)b * 256 + c4]) = o.v;
    }
}

// ---------------------------------------------------------------------------
// mgwoln: merged node+edge Wo+bias+resid -> LN -> bf16 C (verified r17-r20).
// ---------------------------------------------------------------------------
__global__ __launch_bounds__(512) void mgwoln(
    const bf16* __restrict__ An, int Mn,
    const bf16* __restrict__ Ae, int Me,
    const bf16* __restrict__ nBt, const void* __restrict__ nbias,
    const bf16* __restrict__ nresid, const void* __restrict__ nlng, const void* __restrict__ nlnb,
    bf16* __restrict__ Cn,
    const bf16* __restrict__ eBt, const void* __restrict__ ebias,
    const bf16* __restrict__ eresid, const void* __restrict__ elng, const void* __restrict__ elnb,
    bf16* __restrict__ Ce,
    int nby, const int* __restrict__ dflag)
{
    const bool isb = (*dflag != 0);
    __shared__ __align__(16) bf16 Al[128 * 64];   // 16KB (Ps overlay)
    __shared__ __align__(16) bf16 Bl[256 * 64];   // 32KB (Mr/Rsd overlay)
    __shared__ float biasl[256];
    __shared__ float lngl[256];
    __shared__ float lnbl[256];

    const int tid = threadIdx.x;
    const int lane = tid & 63, wave = tid >> 6;
    const int l15 = lane & 15, g = lane >> 4;
    const int t4 = l15 & 3, qd = l15 >> 2;
    const int wr = wave >> 2, wc = wave & 3;   // 2 x 4 wave grid

    const int wg = xcd_swz(blockIdx.y, gridDim.y);
    const bool nodeb = (wg < nby);
    const int rb = (nodeb ? wg : (wg - nby)) * 128;
    const int M = nodeb ? Mn : Me;
    const bf16* A = nodeb ? An : Ae;
    const bf16* Bt = nodeb ? nBt : eBt;
    const void* bias = nodeb ? nbias : ebias;
    const bf16* resid = nodeb ? nresid : eresid;
    const void* lng = nodeb ? nlng : elng;
    const void* lnb = nodeb ? nlnb : elnb;
    bf16* C = nodeb ? Cn : Ce;

    if (tid < 256) {
        biasl[tid] = ldx(bias, tid, isb);
        lngl[tid]  = ldx(lng,  tid, isb);
        lnbl[tid]  = ldx(lnb,  tid, isb);
    }

    const int sp = lane & 7, sr8 = lane >> 3;
    int rlA[2]; long arA[2];
    #pragma unroll
    for (int j = 0; j < 2; j++) {
        const int rl = wave * 16 + j * 8 + sr8;
        rlA[j] = rl;
        const int gm = rb + rl;
        arA[j] = (gm < M) ? gm : (M - 1);
    }
    int rlB[4];
    #pragma unroll
    for (int j = 0; j < 4; j++) rlB[j] = wave * 32 + j * 8 + sr8;

    float4v acc[4][4];
    #pragma unroll
    for (int i = 0; i < 4; i++)
        #pragma unroll
        for (int j = 0; j < 4; j++)
            acc[i][j] = (float4v){0.f, 0.f, 0.f, 0.f};

    for (int k0 = 0; k0 < 256; k0 += 64) {
        #pragma unroll
        for (int j = 0; j < 2; j++) {
            const int pp = sp ^ (rlA[j] & 7);
            gl16(A + arA[j] * 256 + k0 + pp * 8, Al + rlA[j] * 64 + sp * 8);
        }
        #pragma unroll
        for (int j = 0; j < 4; j++) {
            const int pp = sp ^ (rlB[j] & 7);
            gl16(Bt + (size_t)rlB[j] * 256 + k0 + pp * 8, Bl + rlB[j] * 64 + sp * 8);
        }
        __syncthreads();
        #pragma unroll
        for (int ks = 0; ks < 2; ks++) {
            short8v av[4], bv[4];
            #pragma unroll
            for (int mi = 0; mi < 4; mi++) {
                const int row = wr * 64 + mi * 16 + l15;
                const int cp = (ks * 4 + g) ^ (row & 7);
                av[mi] = *reinterpret_cast<const short8v*>(&Al[row * 64 + cp * 8]);
            }
            #pragma unroll
            for (int ni = 0; ni < 4; ni++) {
                const int row = wc * 64 + ni * 16 + l15;
                const int cp = (ks * 4 + g) ^ (row & 7);
                bv[ni] = *reinterpret_cast<const short8v*>(&Bl[row * 64 + cp * 8]);
            }
            #pragma unroll
            for (int mi = 0; mi < 4; mi++)
                #pragma unroll
                for (int ni = 0; ni < 4; ni++)
                    acc[mi][ni] = __builtin_amdgcn_mfma_f32_16x16x32_bf16(
                        av[mi], bv[ni], acc[mi][ni], 0, 0, 0);
        }
        __syncthreads();
    }

    float s1[4] = {0.f,0.f,0.f,0.f}, s2[4] = {0.f,0.f,0.f,0.f};
    #pragma unroll
    for (int mi = 0; mi < 4; mi++) {
        const int grow = rb + wr * 64 + mi * 16 + g * 4 + t4;
        const bool ok = (grow < M);
        #pragma unroll
        for (int ni = 0; ni < 4; ni++) {
            float a[4];
            #pragma unroll
            for (int r = 0; r < 4; r++) a[r] = acc[mi][ni][r];
            quadT(a, t4);
            const int ct = wc * 64 + ni * 16 + qd * 4;
            U4 rr; rr.v = make_int2(0, 0);
            if (ok) rr.v = *reinterpret_cast<const int2*>(&resid[(size_t)grow * 256 + ct]);
            #pragma unroll
            for (int u = 0; u < 4; u++) {
                a[u] += biasl[ct + u] + b2f(rr.h[u]);
                s1[mi] += a[u];
                s2[mi] += a[u] * a[u];
                acc[mi][ni][u] = a[u];
            }
        }
    }
    float* Ps1 = (float*)Al;          // [16][128]
    float* Ps2 = Ps1 + 2048;
    #pragma unroll
    for (int mi = 0; mi < 4; mi++) {
        const int rowl = wr * 64 + mi * 16 + g * 4 + t4;
        Ps1[(wc * 4 + qd) * 128 + rowl] = s1[mi];
        Ps2[(wc * 4 + qd) * 128 + rowl] = s2[mi];
    }
    __syncthreads();
    float* Mr  = (float*)Bl;
    float* Rsd = Mr + 128;
    if (tid < 128) {
        float a1 = 0.f, a2 = 0.f;
        #pragma unroll
        for (int k = 0; k < 16; k++) { a1 += Ps1[k * 128 + tid]; a2 += Ps2[k * 128 + tid]; }
        const float mn = a1 * (1.f / 256.f);
        const float var = a2 * (1.f / 256.f) - mn * mn;
        Mr[tid] = mn;
        Rsd[tid] = rsqrtf(fmaxf(var, 0.f) + 1e-5f);
    }
    __syncthreads();
    #pragma unroll
    for (int mi = 0; mi < 4; mi++) {
        const int rowl = wr * 64 + mi * 16 + g * 4 + t4;
        const int grow = rb + rowl;
        if (grow >= M) continue;
        const float mn = Mr[rowl], rd = Rsd[rowl];
        #pragma unroll
        for (int ni = 0; ni < 4; ni++) {
            const int ct = wc * 64 + ni * 16 + qd * 4;
            U4 ob;
            #pragma unroll
            for (int u = 0; u < 4; u++)
                ob.h[u] = f2b((acc[mi][ni][u] - mn) * rd * lngl[ct + u] + lnbl[ct + u]);
            *reinterpret_cast<int2*>(&C[(size_t)grow * 256 + ct]) = ob.v;
        }
    }
}

// ---------------------------------------------------------------------------
// mgffn1: merged node+edge FFN1 relu(+bias), K=256, NC=1024 (verified r17-r20).
// ---------------------------------------------------------------------------
__global__ __launch_bounds__(256) void mgffn1(
    const bf16* __restrict__ An, int Mn,
    const bf16* __restrict__ Ae, int Me,
    const bf16* __restrict__ nBt, const void* __restrict__ nbias, bf16* __restrict__ Cn,
    const bf16* __restrict__ eBt, const void* __restrict__ ebias, bf16* __restrict__ Ce,
    int nby, const int* __restrict__ dflag)
{
    const bool isb = (*dflag != 0);
    __shared__ __align__(16) bf16 Al[128 * 64];
    __shared__ __align__(16) bf16 Bl[128 * 64];
    __shared__ float biasl[128];

    const int tid = threadIdx.x;
    const int lane = tid & 63, wave = tid >> 6;
    const int l15 = lane & 15, g = lane >> 4;
    const int t4 = l15 & 3, qd = l15 >> 2;
    const int wr = wave >> 1, wc = wave & 1;

    const int nwgx = gridDim.x;   // 8
    int wg = xcd_swz(blockIdx.y * nwgx + blockIdx.x, nwgx * gridDim.y);
    const int by = wg / nwgx, bx = wg % nwgx;
    const bool nodeb = (by < nby);
    const int rb = (nodeb ? by : (by - nby)) * 128;
    const int cb = bx * 128;
    const int M = nodeb ? Mn : Me;
    const bf16* A = nodeb ? An : Ae;
    const bf16* Bt = nodeb ? nBt : eBt;
    const void* bias = nodeb ? nbias : ebias;
    bf16* C = nodeb ? Cn : Ce;

    if (tid < 128) biasl[tid] = ldx(bias, cb + tid, isb);

    const int sp = lane & 7, sr8 = lane >> 3;
    int rls[4]; long arows[4];
    #pragma unroll
    for (int j = 0; j < 4; j++) {
        const int rl = wave * 32 + j * 8 + sr8;
        rls[j] = rl;
        const int gm = rb + rl;
        arows[j] = (gm < M) ? gm : (M - 1);
    }

    float4v acc[4][4];
    #pragma unroll
    for (int i = 0; i < 4; i++)
        #pragma unroll
        for (int j = 0; j < 4; j++)
            acc[i][j] = (float4v){0.f, 0.f, 0.f, 0.f};

    for (int k0 = 0; k0 < 256; k0 += 64) {
        #pragma unroll
        for (int j = 0; j < 4; j++) {
            const int rl = rls[j];
            const int pp = sp ^ (rl & 7);
            gl16(A + arows[j] * 256 + k0 + pp * 8,              Al + rl * 64 + sp * 8);
            gl16(Bt + (size_t)(cb + rl) * 256 + k0 + pp * 8,    Bl + rl * 64 + sp * 8);
        }
        __syncthreads();
        #pragma unroll
        for (int ks = 0; ks < 2; ks++) {
            short8v av[4], bv[4];
            #pragma unroll
            for (int mi = 0; mi < 4; mi++) {
                const int row = wr * 64 + mi * 16 + l15;
                const int cp = (ks * 4 + g) ^ (row & 7);
                av[mi] = *reinterpret_cast<const short8v*>(&Al[row * 64 + cp * 8]);
            }
            #pragma unroll
            for (int ni = 0; ni < 4; ni++) {
                const int row = wc * 64 + ni * 16 + l15;
                const int cp = (ks * 4 + g) ^ (row & 7);
                bv[ni] = *reinterpret_cast<const short8v*>(&Bl[row * 64 + cp * 8]);
            }
            #pragma unroll
            for (int mi = 0; mi < 4; mi++)
                #pragma unroll
                for (int ni = 0; ni < 4; ni++)
                    acc[mi][ni] = __builtin_amdgcn_mfma_f32_16x16x32_bf16(
                        av[mi], bv[ni], acc[mi][ni], 0, 0, 0);
        }
        __syncthreads();
    }

    #pragma unroll
    for (int mi = 0; mi < 4; mi++) {
        const int grow = rb + wr * 64 + mi * 16 + g * 4 + t4;
        const bool ok = (grow < M);
        #pragma unroll
        for (int ni = 0; ni < 4; ni++) {
            float a[4];
            #pragma unroll
            for (int r = 0; r < 4; r++) a[r] = acc[mi][ni][r];
            quadT(a, t4);
            if (!ok) continue;
            const int ct = wc * 64 + ni * 16 + qd * 4;
            U4 o;
            #pragma unroll
            for (int u = 0; u < 4; u++) o.h[u] = f2b(fmaxf(a[u] + biasl[ct + u], 0.f));
            *reinterpret_cast<int2*>(&C[(size_t)grow * 1024 + cb + ct]) = o.v;
        }
    }
}

// ---------------------------------------------------------------------------
// mgffn2: merged node+edge FFN2(+bias+resid) -> LN -> dtype-flex out
// (verified r17-r20).  512 thr, K=1024.
// ---------------------------------------------------------------------------
__global__ __launch_bounds__(512) void mgffn2(
    const bf16* __restrict__ An, int Mn,
    const bf16* __restrict__ Ae, int Me,
    const bf16* __restrict__ nBt, const void* __restrict__ nbias,
    const bf16* __restrict__ nresid, const void* __restrict__ nlng, const void* __restrict__ nlnb,
    long nobase,
    const bf16* __restrict__ eBt, const void* __restrict__ ebias,
    const bf16* __restrict__ eresid, const void* __restrict__ elng, const void* __restrict__ elnb,
    long eobase,
    void* __restrict__ outv,
    int nby, const int* __restrict__ dflag)
{
    const bool isb = (*dflag != 0);
    __shared__ __align__(16) bf16 Al[128 * 64];   // 16KB (Ps overlay)
    __shared__ __align__(16) bf16 Bl[256 * 64];   // 32KB (Mr/Rsd overlay)
    __shared__ float biasl[256];
    __shared__ float lngl[256];
    __shared__ float lnbl[256];

    const int tid = threadIdx.x;
    const int lane = tid & 63, wave = tid >> 6;
    const int l15 = lane & 15, g = lane >> 4;
    const int t4 = l15 & 3, qd = l15 >> 2;
    const int wr = wave >> 2, wc = wave & 3;   // 2 x 4 wave grid

    const int wg = xcd_swz(blockIdx.y, gridDim.y);
    const bool nodeb = (wg < nby);
    const int rb = (nodeb ? wg : (wg - nby)) * 128;
    const int M = nodeb ? Mn : Me;
    const bf16* A = nodeb ? An : Ae;
    const bf16* Bt = nodeb ? nBt : eBt;
    const void* bias = nodeb ? nbias : ebias;
    const bf16* resid = nodeb ? nresid : eresid;
    const void* lng = nodeb ? nlng : elng;
    const void* lnb = nodeb ? nlnb : elnb;
    const long obase = nodeb ? nobase : eobase;

    if (tid < 256) {
        biasl[tid] = ldx(bias, tid, isb);
        lngl[tid]  = ldx(lng,  tid, isb);
        lnbl[tid]  = ldx(lnb,  tid, isb);
    }

    const int sp = lane & 7, sr8 = lane >> 3;
    int rlA[2]; long arA[2];
    #pragma unroll
    for (int j = 0; j < 2; j++) {
        const int rl = wave * 16 + j * 8 + sr8;
        rlA[j] = rl;
        const int gm = rb + rl;
        arA[j] = (gm < M) ? gm : (M - 1);
    }
    int rlB[4];
    #pragma unroll
    for (int j = 0; j < 4; j++) rlB[j] = wave * 32 + j * 8 + sr8;

    float4v acc[4][4];
    #pragma unroll
    for (int i = 0; i < 4; i++)
        #pragma unroll
        for (int j = 0; j < 4; j++)
            acc[i][j] = (float4v){0.f, 0.f, 0.f, 0.f};

    for (int k0 = 0; k0 < 1024; k0 += 64) {
        #pragma unroll
        for (int j = 0; j < 2; j++) {
            const int pp = sp ^ (rlA[j] & 7);
            gl16(A + arA[j] * 1024 + k0 + pp * 8, Al + rlA[j] * 64 + sp * 8);
        }
        #pragma unroll
        for (int j = 0; j < 4; j++) {
            const int pp = sp ^ (rlB[j] & 7);
            gl16(Bt + (size_t)rlB[j] * 1024 + k0 + pp * 8, Bl + rlB[j] * 64 + sp * 8);
        }
        __syncthreads();
        #pragma unroll
        for (int ks = 0; ks < 2; ks++) {
            short8v av[4], bv[4];
            #pragma unroll
            for (int mi = 0; mi < 4; mi++) {
                const int row = wr * 64 + mi * 16 + l15;
                const int cp = (ks * 4 + g) ^ (row & 7);
                av[mi] = *reinterpret_cast<const short8v*>(&Al[row * 64 + cp * 8]);
            }
            #pragma unroll
            for (int ni = 0; ni < 4; ni++) {
                const int row = wc * 64 + ni * 16 + l15;
                const int cp = (ks * 4 + g) ^ (row & 7);
                bv[ni] = *reinterpret_cast<const short8v*>(&Bl[row * 64 + cp * 8]);
            }
            #pragma unroll
            for (int mi = 0; mi < 4; mi++)
                #pragma unroll
                for (int ni = 0; ni < 4; ni++)
                    acc[mi][ni] = __builtin_amdgcn_mfma_f32_16x16x32_bf16(
                        av[mi], bv[ni], acc[mi][ni], 0, 0, 0);
        }
        __syncthreads();
    }

    float s1[4] = {0.f,0.f,0.f,0.f}, s2[4] = {0.f,0.f,0.f,0.f};
    #pragma unroll
    for (int mi = 0; mi < 4; mi++) {
        const int grow = rb + wr * 64 + mi * 16 + g * 4 + t4;
        const bool ok = (grow < M);
        #pragma unroll
        for (int ni = 0; ni < 4; ni++) {
            float a[4];
            #pragma unroll
            for (int r = 0; r < 4; r++) a[r] = acc[mi][ni][r];
            quadT(a, t4);
            const int ct = wc * 64 + ni * 16 + qd * 4;
            U4 rr; rr.v = make_int2(0, 0);
            if (ok) rr.v = *reinterpret_cast<const int2*>(&resid[(size_t)grow * 256 + ct]);
            #pragma unroll
            for (int u = 0; u < 4; u++) {
                a[u] += biasl[ct + u] + b2f(rr.h[u]);
                s1[mi] += a[u];
                s2[mi] += a[u] * a[u];
                acc[mi][ni][u] = a[u];
            }
        }
    }
    float* Ps1 = (float*)Al;          // [16][128]
    float* Ps2 = Ps1 + 2048;
    #pragma unroll
    for (int mi = 0; mi < 4; mi++) {
        const int rowl = wr * 64 + mi * 16 + g * 4 + t4;
        Ps1[(wc * 4 + qd) * 128 + rowl] = s1[mi];
        Ps2[(wc * 4 + qd) * 128 + rowl] = s2[mi];
    }
    __syncthreads();
    float* Mr  = (float*)Bl;
    float* Rsd = Mr + 128;
    if (tid < 128) {
        float a1 = 0.f, a2 = 0.f;
        #pragma unroll
        for (int k = 0; k < 16; k++) { a1 += Ps1[k * 128 + tid]; a2 += Ps2[k * 128 + tid]; }
        const float mn = a1 * (1.f / 256.f);
        const float var = a2 * (1.f / 256.f) - mn * mn;
        Mr[tid] = mn;
        Rsd[tid] = rsqrtf(fmaxf(var, 0.f) + 1e-5f);
    }
    __syncthreads();
    #pragma unroll
    for (int mi = 0; mi < 4; mi++) {
        const int rowl = wr * 64 + mi * 16 + g * 4 + t4;
        const int grow = rb + rowl;
        if (grow >= M) continue;
        const float mn = Mr[rowl], rd = Rsd[rowl];
        #pragma unroll
        for (int ni = 0; ni < 4; ni++) {
            const int ct = wc * 64 + ni * 16 + qd * 4;
            float o[4];
            #pragma unroll
            for (int u = 0; u < 4; u++)
                o[u] = (acc[mi][ni][u] - mn) * rd * lngl[ct + u] + lnbl[ct + u];
            if (isb) {
                U4 ob;
                #pragma unroll
                for (int u = 0; u < 4; u++) ob.h[u] = f2b(o[u]);
                *reinterpret_cast<int2*>((bf16*)outv + obase + (size_t)grow * 256 + ct) = ob.v;
            } else {
                float4 f4 = make_float4(o[0], o[1], o[2], o[3]);
                *reinterpret_cast<float4*>((float*)outv + obase + (size_t)grow * 256 + ct) = f4;
            }
        }
    }
}

// ---------------------------------------------------------------------------
extern "C" void kernel_launch(void* const* d_in, const int* in_sizes, int n_in,
                              void* d_out, int out_size, void* d_ws, size_t ws_size,
                              hipStream_t stream)
{
    const void* x   = d_in[0];
    const void* lgx = d_in[1];
    const int* local_src = (const int*)d_in[3];
    const int* lg_src    = (const int*)d_in[5];
    const int* src_ids   = (const int*)d_in[7];
    const int* dst_ids   = (const int*)d_in[8];

    const void *nWq = d_in[9],  *nbq = d_in[10], *nWk = d_in[11], *nWv = d_in[12],
               *nWo = d_in[13], *nbo = d_in[14], *nln1g = d_in[15], *nln1b = d_in[16],
               *nW1 = d_in[17], *nb1 = d_in[18], *nW2 = d_in[19], *nb2 = d_in[20],
               *nln2g = d_in[21], *nln2b = d_in[22];
    const void *eWq = d_in[23], *ebq = d_in[24], *eWk = d_in[25], *eWv = d_in[26],
               *eWo = d_in[27], *ebo = d_in[28], *eln1g = d_in[29], *eln1b = d_in[30],
               *eW1 = d_in[31], *eb1 = d_in[32], *eW2 = d_in[33], *eb2 = d_in[34],
               *eln2g = d_in[35], *eln2b = d_in[36];

    const dim3 blk(256);
    const dim3 blk2(512);

    // ===== ws layout (elements, bf16).  FE overlays [KVE..OE) which is dead
    // by the time mgffn1 runs.  fixed total = 545.9 MB < ~696 MB measured.
    int* dflag = (int*)d_ws;
    detect_dtype<<<1, 64, 0, stream>>>((const unsigned short*)x, dflag);

    bf16* pk = (bf16*)((char*)d_ws + 256);
    bf16 *pnWq = pk,            *pnWk = pk + 65536,   *pnWv = pk + 131072,
         *pnWo = pk + 196608,   *peWq = pk + 262144,  *peWk = pk + 327680,
         *peWv = pk + 393216,   *peWo = pk + 458752,
         *pnW1 = pk + 524288,   *pnW2 = pk + 786432,
         *peW1 = pk + 1048576,  *peW2 = pk + 1310720;
    bf16* x16   = pk + 1572864;                        //  2,560,000 elems
    bf16* lgx16 = x16 + 2560000;                       // 40,960,000
    bf16* KVE   = lgx16 + 40960000;                    // 81,920,000  (overlay start)
    bf16* QE    = KVE + 81920000;                      // 40,960,000
    bf16* QKVN  = QE + 40960000;                       //  7,680,000
    bf16* OE    = QKVN + 7680000;                      // 40,960,000  (overlay end: 171.52M elems)
    bf16* ON    = OE + 40960000;                       //  2,560,000
    bf16* HN    = ON + 2560000;                        //  2,560,000
    bf16* FN    = HN + 2560000;                        // 10,240,000
    bf16* HE    = FN + 10240000;                       // 40,960,000
    bf16* FE    = KVE;                                 // overlay: 163,840,000 <= 171,520,000

    cvt_both<<<21250, blk, 0, stream>>>(x, lgx, x16, lgx16, dflag);

    PackArgs pa;
    pa.src[0] = nWq; pa.src[1] = nWk; pa.src[2] = nWv; pa.src[3] = nWo;
    pa.src[4] = eWq; pa.src[5] = eWk; pa.src[6] = eWv; pa.src[7] = eWo;
    pa.src[8] = nW1; pa.src[9] = nW2; pa.src[10] = eW1; pa.src[11] = eW2;
    pa.dst[0] = pnWq; pa.dst[1] = pnWk; pa.dst[2] = pnWv; pa.dst[3] = pnWo;
    pa.dst[4] = peWq; pa.dst[5] = peWk; pa.dst[6] = peWv; pa.dst[7] = peWo;
    pa.dst[8] = pnW1; pa.dst[9] = pnW2; pa.dst[10] = peW1; pa.dst[11] = peW2;
    pack_all<<<6144, blk, 0, stream>>>(pa, dflag);

    const int nby = (N_NODES + 127) / 128;   // 79
    const int eby = (E_EDGES + 127) / 128;   // 1250

    // stage 1: merged QKV (node + edge)
    mgqkv<<<dim3(6, nby + eby), blk, 0, stream>>>(
        x16, N_NODES, lgx16, E_EDGES,
        pnWq, pnWk, pnWv, nbq,
        peWq, peWk, peWv, ebq,
        x16, src_ids, dst_ids,
        QKVN, QE, KVE, nby, dflag);

    // stage 2: merged attention
    const int nab = (N_NODES + 3) / 4;        // 2500
    const int eab = (E_EDGES + 3) / 4;        // 40000
    mgattn<<<nab + eab, blk, 0, stream>>>(
        QKVN, local_src, lgx16, ON, QE, KVE, lg_src, OE, nab);

    // stage 3: merged Wo + LN1
    mgwoln<<<dim3(1, nby + eby), blk2, 0, stream>>>(
        ON, N_NODES, OE, E_EDGES,
        pnWo, nbo, x16, nln1g, nln1b, HN,
        peWo, ebo, lgx16, eln1g, eln1b, HE,
        nby, dflag);

    // stage 4: merged FFN1 (full E, FE overlays dead buffers)
    mgffn1<<<dim3(8, nby + eby), blk, 0, stream>>>(
        HN, N_NODES, HE, E_EDGES,
        pnW1, nb1, FN,
        peW1, eb1, FE,
        nby, dflag);

    // stage 5: merged FFN2 + LN2 -> out
    mgffn2<<<dim3(1, nby + eby), blk2, 0, stream>>>(
        FN, N_NODES, FE, E_EDGES,
        pnW2, nb2, HN, nln2g, nln2b, 0L,
        peW2, eb2, HE, eln2g, eln2b, (long)N_NODES * 256,
        d_out, nby, dflag);
}